// Round 2
// baseline (2965.555 us; speedup 1.0000x reference)
//
#include <hip/hip_runtime.h>
#include <hip/hip_bf16.h>
#include <stdint.h>

// QuantizedLinear: Y[M][N] = scale * (X[M][K] @ W[N][K]^T) + bias[N]
// M=8192 (B*S), K=4096, N=16384. X fp32, W int32 (harness widens int8->int32),
// out fp32. Round 2: fix W dtype (int32, not int8). 128x128 bf16-MFMA GEMM,
// reg-staged LDS (both operands need dtype conversion).

#define BM 128
#define BN 128
#define BK 64
#define LDK (BK * 2)  // bytes per LDS row (128 B)

typedef __attribute__((ext_vector_type(4))) float f32x4;
typedef __attribute__((ext_vector_type(4))) int i32x4;
typedef __attribute__((ext_vector_type(8))) short bf16x8s;  // 8 bf16 (4 VGPRs)
typedef __attribute__((ext_vector_type(4))) unsigned int u32x4;

// fp32 -> bf16 round-to-nearest-even (inputs are normal floats)
__device__ __forceinline__ uint32_t f2bf_rne(float f) {
  uint32_t x = __float_as_uint(f);
  return (x + 0x7FFFu + ((x >> 16) & 1u)) >> 16;
}
__device__ __forceinline__ uint32_t pk2_rne(float lo, float hi) {
  return f2bf_rne(lo) | (f2bf_rne(hi) << 16);
}
// exact pack for values already representable in bf16 (|int| <= 256)
__device__ __forceinline__ uint32_t pk2_trunc(float lo, float hi) {
  return (__float_as_uint(lo) >> 16) | (__float_as_uint(hi) & 0xFFFF0000u);
}

__global__ __launch_bounds__(256, 2) void qlinear_gemm_kernel(
    const float* __restrict__ X,      // [M][K] fp32
    const int32_t* __restrict__ W,    // [N][K] int32 in [-127,127]
    const float* __restrict__ scalep,
    const float* __restrict__ bias,   // [N] fp32
    float* __restrict__ Y)            // [M][N] fp32
{
  constexpr int M = 8192, N = 16384, K = 4096;

  __shared__ __align__(16) char lds[(BM + BN) * LDK];  // 32 KiB
  char* As = lds;             // BM rows x 128B (swizzled)
  char* Bs = lds + BM * LDK;  // BN rows x 128B (swizzled)

  const int tid  = threadIdx.x;
  const int lane = tid & 63;
  const int wid  = tid >> 6;
  const int wr   = wid >> 1;   // 2x2 wave grid; each wave owns 64x64
  const int wc   = wid & 1;

  // XCD-aware swizzle: nwg = 8192, divisible by 8 -> simple form is bijective
  const int nwg = gridDim.x;
  const int cpx = nwg >> 3;
  const int bid = blockIdx.x;
  const int swz = (bid & 7) * cpx + (bid >> 3);
  const int ntn = N / BN;  // 128
  const int bm  = swz / ntn;
  const int bn  = swz % ntn;

  const int r16 = lane & 15;  // fragment row/col index
  const int g4  = lane >> 4;  // k-group

  f32x4 acc[4][4];
#pragma unroll
  for (int i = 0; i < 4; ++i)
#pragma unroll
    for (int j = 0; j < 4; ++j) acc[i][j] = (f32x4)0.f;

  const float*   Abase = X + (size_t)(bm * BM) * K;
  const int32_t* Bbase = W + (size_t)(bn * BN) * K;

  const int stg_col = (tid & 7) * 8;  // 8 elems per thread per row-chunk

  const int NT = K / BK;  // 64
  for (int kt = 0; kt < NT; ++kt) {
    const int kb = kt * BK;
    if (kt) __syncthreads();  // previous tile's compute done before overwrite

    // ---- stage A: 128x64 fp32 -> bf16 (RNE). 4 iters x 8 elems/thread.
#pragma unroll
    for (int i = 0; i < 4; ++i) {
      const int row = i * 32 + (tid >> 3);
      const float* p = Abase + (size_t)row * K + kb + stg_col;
      f32x4 v0 = *(const f32x4*)p;
      f32x4 v1 = *(const f32x4*)(p + 4);
      u32x4 o;
      o.x = pk2_rne(v0.x, v0.y);
      o.y = pk2_rne(v0.z, v0.w);
      o.z = pk2_rne(v1.x, v1.y);
      o.w = pk2_rne(v1.z, v1.w);
      int byte = row * LDK + stg_col * 2;
      byte ^= (row & 7) << 4;  // G4 bank-conflict swizzle
      *(u32x4*)(As + byte) = o;
    }

    // ---- stage B: 128x64 int32 -> bf16 (exact). 4 iters x 8 elems/thread.
#pragma unroll
    for (int i = 0; i < 4; ++i) {
      const int row = i * 32 + (tid >> 3);
      const int32_t* p = Bbase + (size_t)row * K + kb + stg_col;
      i32x4 v0 = *(const i32x4*)p;
      i32x4 v1 = *(const i32x4*)(p + 4);
      u32x4 o;
      o.x = pk2_trunc((float)v0.x, (float)v0.y);
      o.y = pk2_trunc((float)v0.z, (float)v0.w);
      o.z = pk2_trunc((float)v1.x, (float)v1.y);
      o.w = pk2_trunc((float)v1.z, (float)v1.w);
      int byte = row * LDK + stg_col * 2;
      byte ^= (row & 7) << 4;
      *(u32x4*)(Bs + byte) = o;
    }

    __syncthreads();

    // ---- compute: 2 k-subtiles x 16 MFMAs per wave
#pragma unroll
    for (int kk = 0; kk < 2; ++kk) {
      bf16x8s af[4], bfr[4];
#pragma unroll
      for (int mi = 0; mi < 4; ++mi) {
        const int row = wr * 64 + mi * 16 + r16;
        int byte = row * LDK + kk * 64 + g4 * 16;
        byte ^= (row & 7) << 4;
        af[mi] = *(const bf16x8s*)(As + byte);
      }
#pragma unroll
      for (int ni = 0; ni < 4; ++ni) {
        const int row = wc * 64 + ni * 16 + r16;
        int byte = row * LDK + kk * 64 + g4 * 16;
        byte ^= (row & 7) << 4;
        bfr[ni] = *(const bf16x8s*)(Bs + byte);
      }
#pragma unroll
      for (int mi = 0; mi < 4; ++mi)
#pragma unroll
        for (int ni = 0; ni < 4; ++ni)
          acc[mi][ni] = __builtin_amdgcn_mfma_f32_16x16x32_bf16(
              af[mi], bfr[ni], acc[mi][ni], 0, 0, 0);
    }
  }

  // ---- epilogue: y = scale*acc + bias
  // C/D layout: col = lane&15, row = (lane>>4)*4 + reg  [m89/m91-verified]
  const float s = scalep[0];
  float bv[4];
#pragma unroll
  for (int ni = 0; ni < 4; ++ni)
    bv[ni] = bias[bn * BN + wc * 64 + ni * 16 + r16];

#pragma unroll
  for (int mi = 0; mi < 4; ++mi) {
    const int grow0 = bm * BM + wr * 64 + mi * 16 + g4 * 4;
#pragma unroll
    for (int r = 0; r < 4; ++r) {
      float* yp = Y + (size_t)(grow0 + r) * N + bn * BN + wc * 64 + r16;
#pragma unroll
      for (int ni = 0; ni < 4; ++ni)
        yp[ni * 16] = s * acc[mi][ni][r] + bv[ni];
    }
  }
}

extern "C" void kernel_launch(void* const* d_in, const int* in_sizes, int n_in,
                              void* d_out, int out_size, void* d_ws, size_t ws_size,
                              hipStream_t stream) {
  const float*   x  = (const float*)d_in[0];
  const int32_t* w  = (const int32_t*)d_in[1];
  const float*   sc = (const float*)d_in[2];
  const float*   bs = (const float*)d_in[3];
  float*         y  = (float*)d_out;

  // grid = (M/BM) * (N/BN) = 64 * 128 = 8192 blocks
  dim3 grid(8192), block(256);
  hipLaunchKernelGGL(qlinear_gemm_kernel, grid, block, 0, stream, x, w, sc, bs, y);
}

// Round 3
// 1418.770 us; speedup vs baseline: 2.0902x; 2.0902x over previous
//
#include <hip/hip_runtime.h>
#include <hip/hip_bf16.h>
#include <stdint.h>

// QuantizedLinear: Y[M][N] = scale * (X[M][K] @ W[N][K]^T) + bias[N]
// M=8192, K=4096, N=16384. X fp32, W int32 (harness widens int8), out fp32.
// Round 3: pre-convert x,W -> bf16 in d_ws (192 MB, L3-resident), then
// m97-structure 128x128 GEMM with global_load_lds width=16 staging.

#define BM 128
#define BN 128
#define BK 64
#define LDK (BK * 2)  // 128 B per LDS row

typedef __attribute__((ext_vector_type(4))) float f32x4;
typedef __attribute__((ext_vector_type(4))) int i32x4;
typedef __attribute__((ext_vector_type(8))) short bf16x8s;
typedef __attribute__((ext_vector_type(4))) unsigned int u32x4;

__device__ __forceinline__ uint32_t f2bf_rne(float f) {
  uint32_t x = __float_as_uint(f);
  return (x + 0x7FFFu + ((x >> 16) & 1u)) >> 16;
}
__device__ __forceinline__ uint32_t pk2_rne(float lo, float hi) {
  return f2bf_rne(lo) | (f2bf_rne(hi) << 16);
}
// exact pack for floats whose low 16 mantissa bits are zero (small ints)
__device__ __forceinline__ uint32_t pk2_trunc(float lo, float hi) {
  return (__float_as_uint(lo) >> 16) | (__float_as_uint(hi) & 0xFFFF0000u);
}

#define GLOAD_LDS16(g, l)                                        \
  __builtin_amdgcn_global_load_lds(                              \
      (const __attribute__((address_space(1))) void*)(g),        \
      (__attribute__((address_space(3))) void*)(l), 16, 0, 0)

// ---------------- conversion kernels ----------------
__global__ __launch_bounds__(256) void conv_x_kernel(
    const float* __restrict__ x, uint16_t* __restrict__ out, int n8) {
  const int stride = blockDim.x * gridDim.x;
  for (int i = blockIdx.x * blockDim.x + threadIdx.x; i < n8; i += stride) {
    f32x4 v0 = ((const f32x4*)x)[i * 2];
    f32x4 v1 = ((const f32x4*)x)[i * 2 + 1];
    u32x4 o;
    o.x = pk2_rne(v0.x, v0.y);
    o.y = pk2_rne(v0.z, v0.w);
    o.z = pk2_rne(v1.x, v1.y);
    o.w = pk2_rne(v1.z, v1.w);
    ((u32x4*)out)[i] = o;
  }
}

__global__ __launch_bounds__(256) void conv_w_kernel(
    const int32_t* __restrict__ w, uint16_t* __restrict__ out, int n8) {
  const int stride = blockDim.x * gridDim.x;
  for (int i = blockIdx.x * blockDim.x + threadIdx.x; i < n8; i += stride) {
    i32x4 v0 = ((const i32x4*)w)[i * 2];
    i32x4 v1 = ((const i32x4*)w)[i * 2 + 1];
    u32x4 o;
    o.x = pk2_trunc((float)v0.x, (float)v0.y);
    o.y = pk2_trunc((float)v0.z, (float)v0.w);
    o.z = pk2_trunc((float)v1.x, (float)v1.y);
    o.w = pk2_trunc((float)v1.z, (float)v1.w);
    ((u32x4*)out)[i] = o;
  }
}

// ---------------- main GEMM (bf16 inputs from ws) ----------------
__global__ __launch_bounds__(256, 3) void qlinear_gemm_bf16_kernel(
    const uint16_t* __restrict__ Xb,  // [M][K] bf16
    const uint16_t* __restrict__ Wb,  // [N][K] bf16
    const float* __restrict__ scalep,
    const float* __restrict__ bias,
    float* __restrict__ Y)
{
  constexpr int M = 8192, N = 16384, K = 4096;
  constexpr int RSB = K * 2;  // row stride bytes

  __shared__ __align__(16) char As[BM * LDK];  // 16 KiB, linear
  __shared__ __align__(16) char Bs[BN * LDK];  // 16 KiB, linear

  const int tid  = threadIdx.x;
  const int lane = tid & 63;
  const int wid  = tid >> 6;
  const int wr   = wid >> 1;  // 2x2 waves, 64x64 each
  const int wc   = wid & 1;

  // XCD swizzle (nwg=8192, %8==0 -> bijective)
  const int nwg = gridDim.x;
  const int cpx = nwg >> 3;
  const int bid = blockIdx.x;
  const int swz = (bid & 7) * cpx + (bid >> 3);
  const int ntn = N / BN;  // 128
  const int bm  = swz / ntn;
  const int bn  = swz % ntn;

  const int r16 = lane & 15;
  const int g4  = lane >> 4;

  f32x4 acc[4][4];
#pragma unroll
  for (int i = 0; i < 4; ++i)
#pragma unroll
    for (int j = 0; j < 4; ++j) acc[i][j] = (f32x4)0.f;

  const char* Abase = (const char*)Xb + (size_t)(bm * BM) * RSB;
  const char* Bbase = (const char*)Wb + (size_t)(bn * BN) * RSB;

  // staging geometry: per wave-issue 64 lanes x 16 B = 1024 B = 8 rows.
  // wave w covers rows [w*32, w*32+32), 4 issues each.
  const int srow = (lane >> 3);        // 0..7 within an issue
  const int scb  = (lane & 7) * 16;    // byte col 0..112

  const int NT = K / BK;  // 64
  for (int kt = 0; kt < NT; ++kt) {
    const size_t kb2 = (size_t)(kt * BK) * 2;  // byte offset into row
    if (kt) __syncthreads();

#pragma unroll
    for (int i = 0; i < 4; ++i) {
      const int r = wid * 32 + i * 8 + srow;
      GLOAD_LDS16(Abase + (size_t)r * RSB + kb2 + scb,
                  As + wid * 4096 + i * 1024);
      GLOAD_LDS16(Bbase + (size_t)r * RSB + kb2 + scb,
                  Bs + wid * 4096 + i * 1024);
    }

    __syncthreads();

#pragma unroll
    for (int kk = 0; kk < 2; ++kk) {
      bf16x8s af[4], bfr[4];
#pragma unroll
      for (int mi = 0; mi < 4; ++mi) {
        const int row = wr * 64 + mi * 16 + r16;
        af[mi] = *(const bf16x8s*)(As + row * LDK + kk * 64 + g4 * 16);
      }
#pragma unroll
      for (int ni = 0; ni < 4; ++ni) {
        const int row = wc * 64 + ni * 16 + r16;
        bfr[ni] = *(const bf16x8s*)(Bs + row * LDK + kk * 64 + g4 * 16);
      }
#pragma unroll
      for (int mi = 0; mi < 4; ++mi)
#pragma unroll
        for (int ni = 0; ni < 4; ++ni)
          acc[mi][ni] = __builtin_amdgcn_mfma_f32_16x16x32_bf16(
              af[mi], bfr[ni], acc[mi][ni], 0, 0, 0);
    }
  }

  // epilogue: y = scale*acc + bias. C/D: col=lane&15, row=(lane>>4)*4+reg
  const float s = scalep[0];
  float bv[4];
#pragma unroll
  for (int ni = 0; ni < 4; ++ni)
    bv[ni] = bias[bn * BN + wc * 64 + ni * 16 + r16];

#pragma unroll
  for (int mi = 0; mi < 4; ++mi) {
    const int grow0 = bm * BM + wr * 64 + mi * 16 + g4 * 4;
#pragma unroll
    for (int r = 0; r < 4; ++r) {
      float* yp = Y + (size_t)(grow0 + r) * N + bn * BN + wc * 64 + r16;
#pragma unroll
      for (int ni = 0; ni < 4; ++ni)
        yp[ni * 16] = s * acc[mi][ni][r] + bv[ni];
    }
  }
}

// ---------------- fallback: round-2 fused kernel (if ws too small) ----------
__global__ __launch_bounds__(256, 2) void qlinear_fused_kernel(
    const float* __restrict__ X, const int32_t* __restrict__ W,
    const float* __restrict__ scalep, const float* __restrict__ bias,
    float* __restrict__ Y)
{
  constexpr int N = 16384, K = 4096;
  __shared__ __align__(16) char lds[(BM + BN) * LDK];
  char* As = lds;
  char* Bs = lds + BM * LDK;
  const int tid = threadIdx.x, lane = tid & 63, wid = tid >> 6;
  const int wr = wid >> 1, wc = wid & 1;
  const int nwg = gridDim.x, cpx = nwg >> 3, bid = blockIdx.x;
  const int swz = (bid & 7) * cpx + (bid >> 3);
  const int ntn = N / BN, bm = swz / ntn, bn = swz % ntn;
  const int r16 = lane & 15, g4 = lane >> 4;
  f32x4 acc[4][4];
#pragma unroll
  for (int i = 0; i < 4; ++i)
#pragma unroll
    for (int j = 0; j < 4; ++j) acc[i][j] = (f32x4)0.f;
  const float* Abase = X + (size_t)(bm * BM) * K;
  const int32_t* Bbase = W + (size_t)(bn * BN) * K;
  const int stg_col = (tid & 7) * 8;
  for (int kt = 0; kt < K / BK; ++kt) {
    const int kb = kt * BK;
    if (kt) __syncthreads();
#pragma unroll
    for (int i = 0; i < 4; ++i) {
      const int row = i * 32 + (tid >> 3);
      const float* p = Abase + (size_t)row * K + kb + stg_col;
      f32x4 v0 = *(const f32x4*)p;
      f32x4 v1 = *(const f32x4*)(p + 4);
      u32x4 o = {pk2_rne(v0.x, v0.y), pk2_rne(v0.z, v0.w),
                 pk2_rne(v1.x, v1.y), pk2_rne(v1.z, v1.w)};
      int byte = row * LDK + stg_col * 2;
      byte ^= (row & 7) << 4;
      *(u32x4*)(As + byte) = o;
    }
#pragma unroll
    for (int i = 0; i < 4; ++i) {
      const int row = i * 32 + (tid >> 3);
      const int32_t* p = Bbase + (size_t)row * K + kb + stg_col;
      i32x4 v0 = *(const i32x4*)p;
      i32x4 v1 = *(const i32x4*)(p + 4);
      u32x4 o = {pk2_trunc((float)v0.x, (float)v0.y),
                 pk2_trunc((float)v0.z, (float)v0.w),
                 pk2_trunc((float)v1.x, (float)v1.y),
                 pk2_trunc((float)v1.z, (float)v1.w)};
      int byte = row * LDK + stg_col * 2;
      byte ^= (row & 7) << 4;
      *(u32x4*)(Bs + byte) = o;
    }
    __syncthreads();
#pragma unroll
    for (int kk = 0; kk < 2; ++kk) {
      bf16x8s af[4], bfr[4];
#pragma unroll
      for (int mi = 0; mi < 4; ++mi) {
        const int row = wr * 64 + mi * 16 + r16;
        int byte = (row * LDK + kk * 64 + g4 * 16) ^ ((row & 7) << 4);
        af[mi] = *(const bf16x8s*)(As + byte);
      }
#pragma unroll
      for (int ni = 0; ni < 4; ++ni) {
        const int row = wc * 64 + ni * 16 + r16;
        int byte = (row * LDK + kk * 64 + g4 * 16) ^ ((row & 7) << 4);
        bfr[ni] = *(const bf16x8s*)(Bs + byte);
      }
#pragma unroll
      for (int mi = 0; mi < 4; ++mi)
#pragma unroll
        for (int ni = 0; ni < 4; ++ni)
          acc[mi][ni] = __builtin_amdgcn_mfma_f32_16x16x32_bf16(
              af[mi], bfr[ni], acc[mi][ni], 0, 0, 0);
    }
  }
  const float s = scalep[0];
  float bv[4];
#pragma unroll
  for (int ni = 0; ni < 4; ++ni)
    bv[ni] = bias[bn * BN + wc * 64 + ni * 16 + r16];
#pragma unroll
  for (int mi = 0; mi < 4; ++mi) {
    const int grow0 = bm * BM + wr * 64 + mi * 16 + g4 * 4;
#pragma unroll
    for (int r = 0; r < 4; ++r) {
      float* yp = Y + (size_t)(grow0 + r) * N + bn * BN + wc * 64 + r16;
#pragma unroll
      for (int ni = 0; ni < 4; ++ni)
        yp[ni * 16] = s * acc[mi][ni][r] + bv[ni];
    }
  }
}

extern "C" void kernel_launch(void* const* d_in, const int* in_sizes, int n_in,
                              void* d_out, int out_size, void* d_ws, size_t ws_size,
                              hipStream_t stream) {
  const float*   x  = (const float*)d_in[0];
  const int32_t* w  = (const int32_t*)d_in[1];
  const float*   sc = (const float*)d_in[2];
  const float*   bs = (const float*)d_in[3];
  float*         y  = (float*)d_out;

  constexpr size_t M = 8192, N = 16384, K = 4096;
  const size_t xb_elems = M * K;          // 33.5M bf16 = 64 MB
  const size_t wb_elems = N * K;          // 67.1M bf16 = 128 MB
  const size_t need = (xb_elems + wb_elems) * 2;

  if (ws_size >= need) {
    uint16_t* xb = (uint16_t*)d_ws;
    uint16_t* wb = xb + xb_elems;
    conv_x_kernel<<<2048, 256, 0, stream>>>(x, xb, (int)(xb_elems / 8));
    conv_w_kernel<<<2048, 256, 0, stream>>>(w, wb, (int)(wb_elems / 8));
    qlinear_gemm_bf16_kernel<<<8192, 256, 0, stream>>>(xb, wb, sc, bs, y);
  } else {
    qlinear_fused_kernel<<<8192, 256, 0, stream>>>(x, w, sc, bs, y);
  }
}

// Round 4
// 1189.286 us; speedup vs baseline: 2.4936x; 1.1930x over previous
//
#include <hip/hip_runtime.h>
#include <hip/hip_bf16.h>
#include <stdint.h>

// QuantizedLinear: Y[M][N] = scale * (X[M][K] @ W[N][K]^T) + bias[N]
// M=8192, K=4096, N=16384. X fp32, W int32 (harness widens int8), out fp32.
// Round 4: pre-convert x,W -> bf16 in d_ws, then 256x256 8-phase GEMM
// (T2 swizzle + T3/T4 counted-vmcnt pipeline + T5 setprio), 8 waves,
// 128 KiB double-buffered LDS, K-half staging units.

typedef __attribute__((ext_vector_type(4))) float f32x4;
typedef __attribute__((ext_vector_type(4))) int i32x4;
typedef __attribute__((ext_vector_type(8))) short bf16x8s;
typedef __attribute__((ext_vector_type(4))) unsigned int u32x4;

__device__ __forceinline__ uint32_t f2bf_rne(float f) {
  uint32_t x = __float_as_uint(f);
  return (x + 0x7FFFu + ((x >> 16) & 1u)) >> 16;
}
__device__ __forceinline__ uint32_t pk2_rne(float lo, float hi) {
  return f2bf_rne(lo) | (f2bf_rne(hi) << 16);
}
__device__ __forceinline__ uint32_t pk2_trunc(float lo, float hi) {
  return (__float_as_uint(lo) >> 16) | (__float_as_uint(hi) & 0xFFFF0000u);
}

#define GLOAD_LDS16(g, l)                                        \
  __builtin_amdgcn_global_load_lds(                              \
      (const __attribute__((address_space(1))) void*)(g),        \
      (__attribute__((address_space(3))) void*)(l), 16, 0, 0)

// ---------------- conversion kernels ----------------
__global__ __launch_bounds__(256) void conv_x_kernel(
    const float* __restrict__ x, uint16_t* __restrict__ out, int n8) {
  const int stride = blockDim.x * gridDim.x;
  for (int i = blockIdx.x * blockDim.x + threadIdx.x; i < n8; i += stride) {
    f32x4 v0 = ((const f32x4*)x)[i * 2];
    f32x4 v1 = ((const f32x4*)x)[i * 2 + 1];
    u32x4 o;
    o.x = pk2_rne(v0.x, v0.y);
    o.y = pk2_rne(v0.z, v0.w);
    o.z = pk2_rne(v1.x, v1.y);
    o.w = pk2_rne(v1.z, v1.w);
    ((u32x4*)out)[i] = o;
  }
}

__global__ __launch_bounds__(256) void conv_w_kernel(
    const int32_t* __restrict__ w, uint16_t* __restrict__ out, int n8) {
  const int stride = blockDim.x * gridDim.x;
  for (int i = blockIdx.x * blockDim.x + threadIdx.x; i < n8; i += stride) {
    i32x4 v0 = ((const i32x4*)w)[i * 2];
    i32x4 v1 = ((const i32x4*)w)[i * 2 + 1];
    u32x4 o;
    o.x = pk2_trunc((float)v0.x, (float)v0.y);
    o.y = pk2_trunc((float)v0.z, (float)v0.w);
    o.z = pk2_trunc((float)v1.x, (float)v1.y);
    o.w = pk2_trunc((float)v1.z, (float)v1.w);
    ((u32x4*)out)[i] = o;
  }
}

// ---------------- 256x256 8-phase GEMM ----------------
// LDS layout (dynamic, 131072 B): buf b at b*65536; A at +0, B at +32768;
// within A/B: K-half block kk at kk*16384 = [256 rows][32 bf16] (64 B rows).
// Swizzle: physical 16B-chunk = logical_chunk ^ ((row>>1)&3)  (involution).
// Staged via pre-swizzled GLOBAL source + linear LDS dest (rule #21).

#define BARPIN()                          \
  __builtin_amdgcn_sched_barrier(0);      \
  __builtin_amdgcn_s_barrier();           \
  __builtin_amdgcn_sched_barrier(0)

#define WAIT8 asm volatile("s_waitcnt vmcnt(8)" ::: "memory"); __builtin_amdgcn_sched_barrier(0)
#define WAIT4 asm volatile("s_waitcnt vmcnt(4)" ::: "memory"); __builtin_amdgcn_sched_barrier(0)
#define WAIT0 asm volatile("s_waitcnt vmcnt(0)" ::: "memory"); __builtin_amdgcn_sched_barrier(0)

// Stage one unit (A or B, one K-half of one tile): 256 rows x 64 B = 16 KB,
// 2 x global_load_lds_dwordx4 per thread (512 threads).
// koffb = (tile*128 + kk*64) byte column offset into the panel row.
#define STAGE(mat_base, koffb, ldsbase)                                      \
  {                                                                          \
    GLOAD_LDS16((mat_base) + (size_t)srow * RSB + (koffb) + skch,            \
                (ldsbase) + tid * 16);                                       \
    GLOAD_LDS16((mat_base) + (size_t)(srow + 128) * RSB + (koffb) + skch,    \
                (ldsbase) + 8192 + tid * 16);                                \
  }

#define ABLK(buf, kk) ((buf) + (kk) * 16384)
#define BBLK(buf, kk) ((buf) + 32768 + (kk) * 16384)

// One phase: (kk-half fixed by bases, mih = M-half). READB: load B-frags
// (else reuse regs from previous phase). STAGE_STMT: 0/1 unit. WAIT_STMT:
// counted vmcnt before the phase-end barrier.
#define PHASE(Abase, Bbase, mih, READB, STAGE_STMT, WAIT_STMT)               \
  {                                                                          \
    if (READB) {                                                             \
      _Pragma("unroll") for (int ni = 0; ni < 4; ++ni) {                     \
        const int r_ = wn * 64 + ni * 16 + r16;                              \
        bq[ni] = *(const bf16x8s*)((Bbase) + r_ * 64 + chb);                 \
      }                                                                      \
    }                                                                        \
    _Pragma("unroll") for (int i = 0; i < 4; ++i) {                          \
      const int r_ = wm * 128 + ((mih) * 4 + i) * 16 + r16;                  \
      aq[i] = *(const bf16x8s*)((Abase) + r_ * 64 + chb);                    \
    }                                                                        \
    STAGE_STMT;                                                              \
    BARPIN();                                                                \
    __builtin_amdgcn_s_setprio(1);                                           \
    _Pragma("unroll") for (int i = 0; i < 4; ++i)                            \
      _Pragma("unroll") for (int ni = 0; ni < 4; ++ni)                       \
        acc[(mih) * 4 + i][ni] = __builtin_amdgcn_mfma_f32_16x16x32_bf16(    \
            aq[i], bq[ni], acc[(mih) * 4 + i][ni], 0, 0, 0);                 \
    __builtin_amdgcn_s_setprio(0);                                           \
    WAIT_STMT;                                                               \
    BARPIN();                                                                \
  }

__global__ __launch_bounds__(512, 2) void qlinear_gemm_256_kernel(
    const uint16_t* __restrict__ Xb,  // [M][K] bf16
    const uint16_t* __restrict__ Wb,  // [N][K] bf16
    const float* __restrict__ scalep,
    const float* __restrict__ bias,
    float* __restrict__ Y)
{
  constexpr int N = 16384, K = 4096;
  constexpr int RSB = K * 2;   // panel row stride, bytes
  constexpr int NT = K / 64;   // 64 K-tiles

  extern __shared__ __align__(16) char lds[];  // 131072 B

  const int tid  = threadIdx.x;
  const int lane = tid & 63;
  const int wid  = tid >> 6;   // 0..7
  const int wm   = wid >> 2;   // 0..1  (M-half of block)
  const int wn   = wid & 3;    // 0..3  (N-quarter of block)
  const int r16  = lane & 15;
  const int g4   = lane >> 4;  // logical k-chunk 0..3
  const int chb  = (g4 ^ ((r16 >> 1) & 3)) << 4;  // swizzled chunk byte off

  // staging geometry (512 threads cover 128 rows x 4 chunks per issue)
  const int srow = tid >> 2;                        // 0..127
  const int skch = ((tid & 3) ^ ((tid >> 3) & 3)) * 16;  // pre-swizzled src col

  // XCD swizzle (nwg = 2048, %8 == 0 -> bijective)
  const int cpx = gridDim.x >> 3;
  const int bid = blockIdx.x;
  const int swz = (bid & 7) * cpx + (bid >> 3);
  const int bm  = swz >> 6;   // / (N/256 = 64)
  const int bn  = swz & 63;

  f32x4 acc[8][4];
#pragma unroll
  for (int i = 0; i < 8; ++i)
#pragma unroll
    for (int j = 0; j < 4; ++j) acc[i][j] = (f32x4)0.f;

  bf16x8s aq[4], bq[4];

  const char* Xp = (const char*)Xb + (size_t)(bm * 256) * RSB;
  const char* Wp = (const char*)Wb + (size_t)(bn * 256) * RSB;

  // ---- prologue: tile0 (both K-halves) + tile1 K-half0 ----
  STAGE(Xp, 0,   ABLK(lds, 0));
  STAGE(Wp, 0,   BBLK(lds, 0));
  STAGE(Xp, 64,  ABLK(lds, 1));
  STAGE(Wp, 64,  BBLK(lds, 1));
  STAGE(Xp, 128, ABLK(lds + 65536, 0));
  STAGE(Wp, 128, BBLK(lds + 65536, 0));
  WAIT8;        // drains tile0 k0 (A,B); leaves 4 units in flight
  BARPIN();

  // ---- main loop: tiles 0 .. NT-3, full stage schedule ----
  for (int t = 0; t <= NT - 3; ++t) {
    char* cb = lds + ((t & 1) << 16);
    char* nb = lds + (((t + 1) & 1) << 16);
    const size_t k1n = (size_t)(t + 1) * 128;
    const size_t k2n = (size_t)(t + 2) * 128;
    // ph0: kk0/mih0, stage A(t+1,k1)   ph1: kk0/mih1, stage B(t+1,k1), wait
    // ph2: kk1/mih0, stage A(t+2,k0)   ph3: kk1/mih1, stage B(t+2,k0), wait
    PHASE(ABLK(cb, 0), BBLK(cb, 0), 0, true,  STAGE(Xp, k1n + 64, ABLK(nb, 1)), );
    PHASE(ABLK(cb, 0), BBLK(cb, 0), 1, false, STAGE(Wp, k1n + 64, BBLK(nb, 1)), WAIT8);
    PHASE(ABLK(cb, 1), BBLK(cb, 1), 0, true,  STAGE(Xp, k2n,      ABLK(cb, 0)), );
    PHASE(ABLK(cb, 1), BBLK(cb, 1), 1, false, STAGE(Wp, k2n,      BBLK(cb, 0)), WAIT8);
  }

  // ---- tail: tile NT-2 (stages only tile NT-1's k1), then tile NT-1 ----
  {
    const int t = NT - 2;
    char* cb = lds + ((t & 1) << 16);
    char* nb = lds + (((t + 1) & 1) << 16);
    const size_t k1n = (size_t)(t + 1) * 128;
    PHASE(ABLK(cb, 0), BBLK(cb, 0), 0, true,  STAGE(Xp, k1n + 64, ABLK(nb, 1)), );
    PHASE(ABLK(cb, 0), BBLK(cb, 0), 1, false, STAGE(Wp, k1n + 64, BBLK(nb, 1)), WAIT8);
    PHASE(ABLK(cb, 1), BBLK(cb, 1), 0, true,  , );
    PHASE(ABLK(cb, 1), BBLK(cb, 1), 1, false, , WAIT4);
  }
  {
    const int t = NT - 1;
    char* cb = lds + ((t & 1) << 16);
    PHASE(ABLK(cb, 0), BBLK(cb, 0), 0, true,  , );
    PHASE(ABLK(cb, 0), BBLK(cb, 0), 1, false, , WAIT0);
    PHASE(ABLK(cb, 1), BBLK(cb, 1), 0, true,  , );
    PHASE(ABLK(cb, 1), BBLK(cb, 1), 1, false, , );
  }

  // ---- epilogue: y = scale*acc + bias ----
  // C/D layout: col = lane&15, row = (lane>>4)*4 + reg  [m89/m91-verified]
  const float s = scalep[0];
  float bv[4];
#pragma unroll
  for (int ni = 0; ni < 4; ++ni)
    bv[ni] = bias[bn * 256 + wn * 64 + ni * 16 + r16];

#pragma unroll
  for (int mi = 0; mi < 8; ++mi) {
    const int grow0 = bm * 256 + wm * 128 + mi * 16 + g4 * 4;
#pragma unroll
    for (int r = 0; r < 4; ++r) {
      float* yp = Y + (size_t)(grow0 + r) * N + bn * 256 + wn * 64 + r16;
#pragma unroll
      for (int ni = 0; ni < 4; ++ni)
        yp[ni * 16] = s * acc[mi][ni][r] + bv[ni];
    }
  }
}

// ---------------- fallback: fused kernel (if ws too small) ----------------
#define BM 128
#define BN 128
#define BK 64
#define LDKF (BK * 2)

__global__ __launch_bounds__(256, 2) void qlinear_fused_kernel(
    const float* __restrict__ X, const int32_t* __restrict__ W,
    const float* __restrict__ scalep, const float* __restrict__ bias,
    float* __restrict__ Y)
{
  constexpr int N = 16384, K = 4096;
  __shared__ __align__(16) char slds[(BM + BN) * LDKF];
  char* As = slds;
  char* Bs = slds + BM * LDKF;
  const int tid = threadIdx.x, lane = tid & 63, wid = tid >> 6;
  const int wr = wid >> 1, wc = wid & 1;
  const int nwg = gridDim.x, cpx = nwg >> 3, bid = blockIdx.x;
  const int swz = (bid & 7) * cpx + (bid >> 3);
  const int ntn = N / BN, bm = swz / ntn, bn = swz % ntn;
  const int r16 = lane & 15, g4 = lane >> 4;
  f32x4 acc[4][4];
#pragma unroll
  for (int i = 0; i < 4; ++i)
#pragma unroll
    for (int j = 0; j < 4; ++j) acc[i][j] = (f32x4)0.f;
  const float* Abase = X + (size_t)(bm * BM) * K;
  const int32_t* Bbase = W + (size_t)(bn * BN) * K;
  const int stg_col = (tid & 7) * 8;
  for (int kt = 0; kt < K / BK; ++kt) {
    const int kb = kt * BK;
    if (kt) __syncthreads();
#pragma unroll
    for (int i = 0; i < 4; ++i) {
      const int row = i * 32 + (tid >> 3);
      const float* p = Abase + (size_t)row * K + kb + stg_col;
      f32x4 v0 = *(const f32x4*)p;
      f32x4 v1 = *(const f32x4*)(p + 4);
      u32x4 o = {pk2_rne(v0.x, v0.y), pk2_rne(v0.z, v0.w),
                 pk2_rne(v1.x, v1.y), pk2_rne(v1.z, v1.w)};
      int byte = (row * LDKF + stg_col * 2) ^ ((row & 7) << 4);
      *(u32x4*)(As + byte) = o;
    }
#pragma unroll
    for (int i = 0; i < 4; ++i) {
      const int row = i * 32 + (tid >> 3);
      const int32_t* p = Bbase + (size_t)row * K + kb + stg_col;
      i32x4 v0 = *(const i32x4*)p;
      i32x4 v1 = *(const i32x4*)(p + 4);
      u32x4 o = {pk2_trunc((float)v0.x, (float)v0.y),
                 pk2_trunc((float)v0.z, (float)v0.w),
                 pk2_trunc((float)v1.x, (float)v1.y),
                 pk2_trunc((float)v1.z, (float)v1.w)};
      int byte = (row * LDKF + stg_col * 2) ^ ((row & 7) << 4);
      *(u32x4*)(Bs + byte) = o;
    }
    __syncthreads();
#pragma unroll
    for (int kk = 0; kk < 2; ++kk) {
      bf16x8s af[4], bfr[4];
#pragma unroll
      for (int mi = 0; mi < 4; ++mi) {
        const int row = wr * 64 + mi * 16 + r16;
        int byte = (row * LDKF + kk * 64 + g4 * 16) ^ ((row & 7) << 4);
        af[mi] = *(const bf16x8s*)(As + byte);
      }
#pragma unroll
      for (int ni = 0; ni < 4; ++ni) {
        const int row = wc * 64 + ni * 16 + r16;
        int byte = (row * LDKF + kk * 64 + g4 * 16) ^ ((row & 7) << 4);
        bfr[ni] = *(const bf16x8s*)(Bs + byte);
      }
#pragma unroll
      for (int mi = 0; mi < 4; ++mi)
#pragma unroll
        for (int ni = 0; ni < 4; ++ni)
          acc[mi][ni] = __builtin_amdgcn_mfma_f32_16x16x32_bf16(
              af[mi], bfr[ni], acc[mi][ni], 0, 0, 0);
    }
  }
  const float s = scalep[0];
  float bv[4];
#pragma unroll
  for (int ni = 0; ni < 4; ++ni)
    bv[ni] = bias[bn * BN + wc * 64 + ni * 16 + r16];
#pragma unroll
  for (int mi = 0; mi < 4; ++mi) {
    const int grow0 = bm * BM + wr * 64 + mi * 16 + g4 * 4;
#pragma unroll
    for (int r = 0; r < 4; ++r) {
      float* yp = Y + (size_t)(grow0 + r) * N + bn * BN + wc * 64 + r16;
#pragma unroll
      for (int ni = 0; ni < 4; ++ni)
        yp[ni * 16] = s * acc[mi][ni][r] + bv[ni];
    }
  }
}

extern "C" void kernel_launch(void* const* d_in, const int* in_sizes, int n_in,
                              void* d_out, int out_size, void* d_ws, size_t ws_size,
                              hipStream_t stream) {
  const float*   x  = (const float*)d_in[0];
  const int32_t* w  = (const int32_t*)d_in[1];
  const float*   sc = (const float*)d_in[2];
  const float*   bs = (const float*)d_in[3];
  float*         y  = (float*)d_out;

  constexpr size_t M = 8192, N = 16384, K = 4096;
  const size_t xb_elems = M * K;   // 64 MB bf16
  const size_t wb_elems = N * K;   // 128 MB bf16
  const size_t need = (xb_elems + wb_elems) * 2;

  if (ws_size >= need) {
    uint16_t* xb = (uint16_t*)d_ws;
    uint16_t* wb = xb + xb_elems;
    hipFuncSetAttribute((const void*)qlinear_gemm_256_kernel,
                        hipFuncAttributeMaxDynamicSharedMemorySize, 131072);
    conv_x_kernel<<<2048, 256, 0, stream>>>(x, xb, (int)(xb_elems / 8));
    conv_w_kernel<<<2048, 256, 0, stream>>>(w, wb, (int)(wb_elems / 8));
    // grid = (M/256) * (N/256) = 32 * 64 = 2048 blocks, 512 threads
    qlinear_gemm_256_kernel<<<2048, 512, 131072, stream>>>(xb, wb, sc, bs, y);
  } else {
    qlinear_fused_kernel<<<8192, 256, 0, stream>>>(x, w, sc, bs, y);
  }
}

// Round 5
// 1130.593 us; speedup vs baseline: 2.6230x; 1.0519x over previous
//
#include <hip/hip_runtime.h>
#include <hip/hip_bf16.h>
#include <stdint.h>

// QuantizedLinear: Y[M][N] = scale * (X[M][K] @ W[N][K]^T) + bias[N]
// M=8192, K=4096, N=16384. X fp32, W int32 (harness widens int8), out fp32.
// Round 5: round-4 structure frozen + non-temporal Y stores (stop L3
// pollution by the 512 MB write stream; keep the 192 MB bf16 operand set
// L3-resident) + non-temporal loads in the conversion kernels.

typedef __attribute__((ext_vector_type(4))) float f32x4;
typedef __attribute__((ext_vector_type(4))) int i32x4;
typedef __attribute__((ext_vector_type(8))) short bf16x8s;
typedef __attribute__((ext_vector_type(4))) unsigned int u32x4;

__device__ __forceinline__ uint32_t f2bf_rne(float f) {
  uint32_t x = __float_as_uint(f);
  return (x + 0x7FFFu + ((x >> 16) & 1u)) >> 16;
}
__device__ __forceinline__ uint32_t pk2_rne(float lo, float hi) {
  return f2bf_rne(lo) | (f2bf_rne(hi) << 16);
}
__device__ __forceinline__ uint32_t pk2_trunc(float lo, float hi) {
  return (__float_as_uint(lo) >> 16) | (__float_as_uint(hi) & 0xFFFF0000u);
}

#define GLOAD_LDS16(g, l)                                        \
  __builtin_amdgcn_global_load_lds(                              \
      (const __attribute__((address_space(1))) void*)(g),        \
      (__attribute__((address_space(3))) void*)(l), 16, 0, 0)

// ---------------- conversion kernels (NT loads: inputs are read-once) ------
__global__ __launch_bounds__(256) void conv_x_kernel(
    const float* __restrict__ x, uint16_t* __restrict__ out, int n8) {
  const int stride = blockDim.x * gridDim.x;
  for (int i = blockIdx.x * blockDim.x + threadIdx.x; i < n8; i += stride) {
    f32x4 v0 = __builtin_nontemporal_load((const f32x4*)x + i * 2);
    f32x4 v1 = __builtin_nontemporal_load((const f32x4*)x + i * 2 + 1);
    u32x4 o;
    o.x = pk2_rne(v0.x, v0.y);
    o.y = pk2_rne(v0.z, v0.w);
    o.z = pk2_rne(v1.x, v1.y);
    o.w = pk2_rne(v1.z, v1.w);
    ((u32x4*)out)[i] = o;
  }
}

__global__ __launch_bounds__(256) void conv_w_kernel(
    const int32_t* __restrict__ w, uint16_t* __restrict__ out, int n8) {
  const int stride = blockDim.x * gridDim.x;
  for (int i = blockIdx.x * blockDim.x + threadIdx.x; i < n8; i += stride) {
    i32x4 v0 = __builtin_nontemporal_load((const i32x4*)w + i * 2);
    i32x4 v1 = __builtin_nontemporal_load((const i32x4*)w + i * 2 + 1);
    u32x4 o;
    o.x = pk2_trunc((float)v0.x, (float)v0.y);
    o.y = pk2_trunc((float)v0.z, (float)v0.w);
    o.z = pk2_trunc((float)v1.x, (float)v1.y);
    o.w = pk2_trunc((float)v1.z, (float)v1.w);
    ((u32x4*)out)[i] = o;
  }
}

// ---------------- 256x256 8-phase GEMM ----------------
// LDS layout (dynamic, 131072 B): buf b at b*65536; A at +0, B at +32768;
// within A/B: K-half block kk at kk*16384 = [256 rows][32 bf16] (64 B rows).
// Swizzle: physical 16B-chunk = logical_chunk ^ ((row>>1)&3)  (involution).
// Staged via pre-swizzled GLOBAL source + linear LDS dest (rule #21).

#define BARPIN()                          \
  __builtin_amdgcn_sched_barrier(0);      \
  __builtin_amdgcn_s_barrier();           \
  __builtin_amdgcn_sched_barrier(0)

#define WAIT8 asm volatile("s_waitcnt vmcnt(8)" ::: "memory"); __builtin_amdgcn_sched_barrier(0)
#define WAIT4 asm volatile("s_waitcnt vmcnt(4)" ::: "memory"); __builtin_amdgcn_sched_barrier(0)
#define WAIT0 asm volatile("s_waitcnt vmcnt(0)" ::: "memory"); __builtin_amdgcn_sched_barrier(0)

#define STAGE(mat_base, koffb, ldsbase)                                      \
  {                                                                          \
    GLOAD_LDS16((mat_base) + (size_t)srow * RSB + (koffb) + skch,            \
                (ldsbase) + tid * 16);                                       \
    GLOAD_LDS16((mat_base) + (size_t)(srow + 128) * RSB + (koffb) + skch,    \
                (ldsbase) + 8192 + tid * 16);                                \
  }

#define ABLK(buf, kk) ((buf) + (kk) * 16384)
#define BBLK(buf, kk) ((buf) + 32768 + (kk) * 16384)

#define PHASE(Abase, Bbase, mih, READB, STAGE_STMT, WAIT_STMT)               \
  {                                                                          \
    if (READB) {                                                             \
      _Pragma("unroll") for (int ni = 0; ni < 4; ++ni) {                     \
        const int r_ = wn * 64 + ni * 16 + r16;                              \
        bq[ni] = *(const bf16x8s*)((Bbase) + r_ * 64 + chb);                 \
      }                                                                      \
    }                                                                        \
    _Pragma("unroll") for (int i = 0; i < 4; ++i) {                          \
      const int r_ = wm * 128 + ((mih) * 4 + i) * 16 + r16;                  \
      aq[i] = *(const bf16x8s*)((Abase) + r_ * 64 + chb);                    \
    }                                                                        \
    STAGE_STMT;                                                              \
    BARPIN();                                                                \
    __builtin_amdgcn_s_setprio(1);                                           \
    _Pragma("unroll") for (int i = 0; i < 4; ++i)                            \
      _Pragma("unroll") for (int ni = 0; ni < 4; ++ni)                       \
        acc[(mih) * 4 + i][ni] = __builtin_amdgcn_mfma_f32_16x16x32_bf16(    \
            aq[i], bq[ni], acc[(mih) * 4 + i][ni], 0, 0, 0);                 \
    __builtin_amdgcn_s_setprio(0);                                           \
    WAIT_STMT;                                                               \
    BARPIN();                                                                \
  }

__global__ __launch_bounds__(512, 2) void qlinear_gemm_256_kernel(
    const uint16_t* __restrict__ Xb,  // [M][K] bf16
    const uint16_t* __restrict__ Wb,  // [N][K] bf16
    const float* __restrict__ scalep,
    const float* __restrict__ bias,
    float* __restrict__ Y)
{
  constexpr int N = 16384, K = 4096;
  constexpr int RSB = K * 2;   // panel row stride, bytes
  constexpr int NT = K / 64;   // 64 K-tiles

  extern __shared__ __align__(16) char lds[];  // 131072 B

  const int tid  = threadIdx.x;
  const int lane = tid & 63;
  const int wid  = tid >> 6;   // 0..7
  const int wm   = wid >> 2;   // 0..1  (M-half of block)
  const int wn   = wid & 3;    // 0..3  (N-quarter of block)
  const int r16  = lane & 15;
  const int g4   = lane >> 4;  // logical k-chunk 0..3
  const int chb  = (g4 ^ ((r16 >> 1) & 3)) << 4;  // swizzled chunk byte off

  const int srow = tid >> 2;                              // 0..127
  const int skch = ((tid & 3) ^ ((tid >> 3) & 3)) * 16;   // pre-swizzled src

  // XCD swizzle (nwg = 2048, %8 == 0 -> bijective)
  const int cpx = gridDim.x >> 3;
  const int bid = blockIdx.x;
  const int swz = (bid & 7) * cpx + (bid >> 3);
  const int bm  = swz >> 6;   // / (N/256 = 64)
  const int bn  = swz & 63;

  f32x4 acc[8][4];
#pragma unroll
  for (int i = 0; i < 8; ++i)
#pragma unroll
    for (int j = 0; j < 4; ++j) acc[i][j] = (f32x4)0.f;

  bf16x8s aq[4], bq[4];

  const char* Xp = (const char*)Xb + (size_t)(bm * 256) * RSB;
  const char* Wp = (const char*)Wb + (size_t)(bn * 256) * RSB;

  // ---- prologue: tile0 (both K-halves) + tile1 K-half0 ----
  STAGE(Xp, 0,   ABLK(lds, 0));
  STAGE(Wp, 0,   BBLK(lds, 0));
  STAGE(Xp, 64,  ABLK(lds, 1));
  STAGE(Wp, 64,  BBLK(lds, 1));
  STAGE(Xp, 128, ABLK(lds + 65536, 0));
  STAGE(Wp, 128, BBLK(lds + 65536, 0));
  WAIT8;        // drains tile0 k0 (A,B); leaves 4 units in flight
  BARPIN();

  // ---- main loop: tiles 0 .. NT-3 ----
  for (int t = 0; t <= NT - 3; ++t) {
    char* cb = lds + ((t & 1) << 16);
    char* nb = lds + (((t + 1) & 1) << 16);
    const size_t k1n = (size_t)(t + 1) * 128;
    const size_t k2n = (size_t)(t + 2) * 128;
    PHASE(ABLK(cb, 0), BBLK(cb, 0), 0, true,  STAGE(Xp, k1n + 64, ABLK(nb, 1)), );
    PHASE(ABLK(cb, 0), BBLK(cb, 0), 1, false, STAGE(Wp, k1n + 64, BBLK(nb, 1)), WAIT8);
    PHASE(ABLK(cb, 1), BBLK(cb, 1), 0, true,  STAGE(Xp, k2n,      ABLK(cb, 0)), );
    PHASE(ABLK(cb, 1), BBLK(cb, 1), 1, false, STAGE(Wp, k2n,      BBLK(cb, 0)), WAIT8);
  }

  // ---- tail ----
  {
    const int t = NT - 2;
    char* cb = lds + ((t & 1) << 16);
    char* nb = lds + (((t + 1) & 1) << 16);
    const size_t k1n = (size_t)(t + 1) * 128;
    PHASE(ABLK(cb, 0), BBLK(cb, 0), 0, true,  STAGE(Xp, k1n + 64, ABLK(nb, 1)), );
    PHASE(ABLK(cb, 0), BBLK(cb, 0), 1, false, STAGE(Wp, k1n + 64, BBLK(nb, 1)), WAIT8);
    PHASE(ABLK(cb, 1), BBLK(cb, 1), 0, true,  , );
    PHASE(ABLK(cb, 1), BBLK(cb, 1), 1, false, , WAIT4);
  }
  {
    const int t = NT - 1;
    char* cb = lds + ((t & 1) << 16);
    PHASE(ABLK(cb, 0), BBLK(cb, 0), 0, true,  , );
    PHASE(ABLK(cb, 0), BBLK(cb, 0), 1, false, , WAIT0);
    PHASE(ABLK(cb, 1), BBLK(cb, 1), 0, true,  , );
    PHASE(ABLK(cb, 1), BBLK(cb, 1), 1, false, , );
  }

  // ---- epilogue: y = scale*acc + bias, NON-TEMPORAL stores ----
  // C/D layout: col = lane&15, row = (lane>>4)*4 + reg  [m89/m91-verified]
  const float s = scalep[0];
  float bv[4];
#pragma unroll
  for (int ni = 0; ni < 4; ++ni)
    bv[ni] = bias[bn * 256 + wn * 64 + ni * 16 + r16];

#pragma unroll
  for (int mi = 0; mi < 8; ++mi) {
    const int grow0 = bm * 256 + wm * 128 + mi * 16 + g4 * 4;
#pragma unroll
    for (int r = 0; r < 4; ++r) {
      float* yp = Y + (size_t)(grow0 + r) * N + bn * 256 + wn * 64 + r16;
#pragma unroll
      for (int ni = 0; ni < 4; ++ni)
        __builtin_nontemporal_store(s * acc[mi][ni][r] + bv[ni], yp + ni * 16);
    }
  }
}

// ---------------- fallback: fused kernel (if ws too small) ----------------
#define BM 128
#define BN 128
#define BK 64
#define LDKF (BK * 2)

__global__ __launch_bounds__(256, 2) void qlinear_fused_kernel(
    const float* __restrict__ X, const int32_t* __restrict__ W,
    const float* __restrict__ scalep, const float* __restrict__ bias,
    float* __restrict__ Y)
{
  constexpr int N = 16384, K = 4096;
  __shared__ __align__(16) char slds[(BM + BN) * LDKF];
  char* As = slds;
  char* Bs = slds + BM * LDKF;
  const int tid = threadIdx.x, lane = tid & 63, wid = tid >> 6;
  const int wr = wid >> 1, wc = wid & 1;
  const int nwg = gridDim.x, cpx = nwg >> 3, bid = blockIdx.x;
  const int swz = (bid & 7) * cpx + (bid >> 3);
  const int ntn = N / BN, bm = swz / ntn, bn = swz % ntn;
  const int r16 = lane & 15, g4 = lane >> 4;
  f32x4 acc[4][4];
#pragma unroll
  for (int i = 0; i < 4; ++i)
#pragma unroll
    for (int j = 0; j < 4; ++j) acc[i][j] = (f32x4)0.f;
  const float* Abase = X + (size_t)(bm * BM) * K;
  const int32_t* Bbase = W + (size_t)(bn * BN) * K;
  const int stg_col = (tid & 7) * 8;
  for (int kt = 0; kt < K / BK; ++kt) {
    const int kb = kt * BK;
    if (kt) __syncthreads();
#pragma unroll
    for (int i = 0; i < 4; ++i) {
      const int row = i * 32 + (tid >> 3);
      const float* p = Abase + (size_t)row * K + kb + stg_col;
      f32x4 v0 = *(const f32x4*)p;
      f32x4 v1 = *(const f32x4*)(p + 4);
      u32x4 o = {pk2_rne(v0.x, v0.y), pk2_rne(v0.z, v0.w),
                 pk2_rne(v1.x, v1.y), pk2_rne(v1.z, v1.w)};
      int byte = (row * LDKF + stg_col * 2) ^ ((row & 7) << 4);
      *(u32x4*)(As + byte) = o;
    }
#pragma unroll
    for (int i = 0; i < 4; ++i) {
      const int row = i * 32 + (tid >> 3);
      const int32_t* p = Bbase + (size_t)row * K + kb + stg_col;
      i32x4 v0 = *(const i32x4*)p;
      i32x4 v1 = *(const i32x4*)(p + 4);
      u32x4 o = {pk2_trunc((float)v0.x, (float)v0.y),
                 pk2_trunc((float)v0.z, (float)v0.w),
                 pk2_trunc((float)v1.x, (float)v1.y),
                 pk2_trunc((float)v1.z, (float)v1.w)};
      int byte = (row * LDKF + stg_col * 2) ^ ((row & 7) << 4);
      *(u32x4*)(Bs + byte) = o;
    }
    __syncthreads();
#pragma unroll
    for (int kk = 0; kk < 2; ++kk) {
      bf16x8s af[4], bfr[4];
#pragma unroll
      for (int mi = 0; mi < 4; ++mi) {
        const int row = wr * 64 + mi * 16 + r16;
        int byte = (row * LDKF + kk * 64 + g4 * 16) ^ ((row & 7) << 4);
        af[mi] = *(const bf16x8s*)(As + byte);
      }
#pragma unroll
      for (int ni = 0; ni < 4; ++ni) {
        const int row = wc * 64 + ni * 16 + r16;
        int byte = (row * LDKF + kk * 64 + g4 * 16) ^ ((row & 7) << 4);
        bfr[ni] = *(const bf16x8s*)(Bs + byte);
      }
#pragma unroll
      for (int mi = 0; mi < 4; ++mi)
#pragma unroll
        for (int ni = 0; ni < 4; ++ni)
          acc[mi][ni] = __builtin_amdgcn_mfma_f32_16x16x32_bf16(
              af[mi], bfr[ni], acc[mi][ni], 0, 0, 0);
    }
  }
  const float s = scalep[0];
  float bv[4];
#pragma unroll
  for (int ni = 0; ni < 4; ++ni)
    bv[ni] = bias[bn * BN + wc * 64 + ni * 16 + r16];
#pragma unroll
  for (int mi = 0; mi < 4; ++mi) {
    const int grow0 = bm * BM + wr * 64 + mi * 16 + g4 * 4;
#pragma unroll
    for (int r = 0; r < 4; ++r) {
      float* yp = Y + (size_t)(grow0 + r) * N + bn * BN + wc * 64 + r16;
#pragma unroll
      for (int ni = 0; ni < 4; ++ni)
        yp[ni * 16] = s * acc[mi][ni][r] + bv[ni];
    }
  }
}

extern "C" void kernel_launch(void* const* d_in, const int* in_sizes, int n_in,
                              void* d_out, int out_size, void* d_ws, size_t ws_size,
                              hipStream_t stream) {
  const float*   x  = (const float*)d_in[0];
  const int32_t* w  = (const int32_t*)d_in[1];
  const float*   sc = (const float*)d_in[2];
  const float*   bs = (const float*)d_in[3];
  float*         y  = (float*)d_out;

  constexpr size_t M = 8192, N = 16384, K = 4096;
  const size_t xb_elems = M * K;   // 64 MB bf16
  const size_t wb_elems = N * K;   // 128 MB bf16
  const size_t need = (xb_elems + wb_elems) * 2;

  if (ws_size >= need) {
    uint16_t* xb = (uint16_t*)d_ws;
    uint16_t* wb = xb + xb_elems;
    hipFuncSetAttribute((const void*)qlinear_gemm_256_kernel,
                        hipFuncAttributeMaxDynamicSharedMemorySize, 131072);
    conv_x_kernel<<<2048, 256, 0, stream>>>(x, xb, (int)(xb_elems / 8));
    conv_w_kernel<<<2048, 256, 0, stream>>>(w, wb, (int)(wb_elems / 8));
    qlinear_gemm_256_kernel<<<2048, 512, 131072, stream>>>(xb, wb, sc, bs, y);
  } else {
    qlinear_fused_kernel<<<8192, 256, 0, stream>>>(x, w, sc, bs, y);
  }
}

// Round 6
// 1016.826 us; speedup vs baseline: 2.9165x; 1.1119x over previous
//
#include <hip/hip_runtime.h>
#include <hip/hip_bf16.h>
#include <stdint.h>

// QuantizedLinear: Y[M][N] = scale * (X[M][K] @ W[N][K]^T) + bias[N]
// M=8192, K=4096, N=16384. X fp32, W int32 (harness widens int8), out fp32.
// Round 6: 2D super-tile block mapping — each XCD owns a 16x16 block patch
// (working set X 64MB + W 128MB = 192MB stays L3-resident; concurrent rows
// share X-panels in per-XCD L2). Y stores back to normal (NT inflated
// WRITE_SIZE +15% with no FETCH benefit). Schedule frozen from round 4.

typedef __attribute__((ext_vector_type(4))) float f32x4;
typedef __attribute__((ext_vector_type(4))) int i32x4;
typedef __attribute__((ext_vector_type(8))) short bf16x8s;
typedef __attribute__((ext_vector_type(4))) unsigned int u32x4;

__device__ __forceinline__ uint32_t f2bf_rne(float f) {
  uint32_t x = __float_as_uint(f);
  return (x + 0x7FFFu + ((x >> 16) & 1u)) >> 16;
}
__device__ __forceinline__ uint32_t pk2_rne(float lo, float hi) {
  return f2bf_rne(lo) | (f2bf_rne(hi) << 16);
}
__device__ __forceinline__ uint32_t pk2_trunc(float lo, float hi) {
  return (__float_as_uint(lo) >> 16) | (__float_as_uint(hi) & 0xFFFF0000u);
}

#define GLOAD_LDS16(g, l)                                        \
  __builtin_amdgcn_global_load_lds(                              \
      (const __attribute__((address_space(1))) void*)(g),        \
      (__attribute__((address_space(3))) void*)(l), 16, 0, 0)

// ---------------- conversion kernels (NT loads: inputs are read-once) ------
__global__ __launch_bounds__(256) void conv_x_kernel(
    const float* __restrict__ x, uint16_t* __restrict__ out, int n8) {
  const int stride = blockDim.x * gridDim.x;
  for (int i = blockIdx.x * blockDim.x + threadIdx.x; i < n8; i += stride) {
    f32x4 v0 = __builtin_nontemporal_load((const f32x4*)x + i * 2);
    f32x4 v1 = __builtin_nontemporal_load((const f32x4*)x + i * 2 + 1);
    u32x4 o;
    o.x = pk2_rne(v0.x, v0.y);
    o.y = pk2_rne(v0.z, v0.w);
    o.z = pk2_rne(v1.x, v1.y);
    o.w = pk2_rne(v1.z, v1.w);
    ((u32x4*)out)[i] = o;
  }
}

__global__ __launch_bounds__(256) void conv_w_kernel(
    const int32_t* __restrict__ w, uint16_t* __restrict__ out, int n8) {
  const int stride = blockDim.x * gridDim.x;
  for (int i = blockIdx.x * blockDim.x + threadIdx.x; i < n8; i += stride) {
    i32x4 v0 = __builtin_nontemporal_load((const i32x4*)w + i * 2);
    i32x4 v1 = __builtin_nontemporal_load((const i32x4*)w + i * 2 + 1);
    u32x4 o;
    o.x = pk2_trunc((float)v0.x, (float)v0.y);
    o.y = pk2_trunc((float)v0.z, (float)v0.w);
    o.z = pk2_trunc((float)v1.x, (float)v1.y);
    o.w = pk2_trunc((float)v1.z, (float)v1.w);
    ((u32x4*)out)[i] = o;
  }
}

// ---------------- 256x256 8-phase GEMM ----------------
// LDS layout (dynamic, 131072 B): buf b at b*65536; A at +0, B at +32768;
// within A/B: K-half block kk at kk*16384 = [256 rows][32 bf16] (64 B rows).
// Swizzle: physical 16B-chunk = logical_chunk ^ ((row>>1)&3)  (involution).
// Staged via pre-swizzled GLOBAL source + linear LDS dest (rule #21).

#define BARPIN()                          \
  __builtin_amdgcn_sched_barrier(0);      \
  __builtin_amdgcn_s_barrier();           \
  __builtin_amdgcn_sched_barrier(0)

#define WAIT8 asm volatile("s_waitcnt vmcnt(8)" ::: "memory"); __builtin_amdgcn_sched_barrier(0)
#define WAIT4 asm volatile("s_waitcnt vmcnt(4)" ::: "memory"); __builtin_amdgcn_sched_barrier(0)
#define WAIT0 asm volatile("s_waitcnt vmcnt(0)" ::: "memory"); __builtin_amdgcn_sched_barrier(0)

#define STAGE(mat_base, koffb, ldsbase)                                      \
  {                                                                          \
    GLOAD_LDS16((mat_base) + (size_t)srow * RSB + (koffb) + skch,            \
                (ldsbase) + tid * 16);                                       \
    GLOAD_LDS16((mat_base) + (size_t)(srow + 128) * RSB + (koffb) + skch,    \
                (ldsbase) + 8192 + tid * 16);                                \
  }

#define ABLK(buf, kk) ((buf) + (kk) * 16384)
#define BBLK(buf, kk) ((buf) + 32768 + (kk) * 16384)

#define PHASE(Abase, Bbase, mih, READB, STAGE_STMT, WAIT_STMT)               \
  {                                                                          \
    if (READB) {                                                             \
      _Pragma("unroll") for (int ni = 0; ni < 4; ++ni) {                     \
        const int r_ = wn * 64 + ni * 16 + r16;                              \
        bq[ni] = *(const bf16x8s*)((Bbase) + r_ * 64 + chb);                 \
      }                                                                      \
    }                                                                        \
    _Pragma("unroll") for (int i = 0; i < 4; ++i) {                          \
      const int r_ = wm * 128 + ((mih) * 4 + i) * 16 + r16;                  \
      aq[i] = *(const bf16x8s*)((Abase) + r_ * 64 + chb);                    \
    }                                                                        \
    STAGE_STMT;                                                              \
    BARPIN();                                                                \
    __builtin_amdgcn_s_setprio(1);                                           \
    _Pragma("unroll") for (int i = 0; i < 4; ++i)                            \
      _Pragma("unroll") for (int ni = 0; ni < 4; ++ni)                       \
        acc[(mih) * 4 + i][ni] = __builtin_amdgcn_mfma_f32_16x16x32_bf16(    \
            aq[i], bq[ni], acc[(mih) * 4 + i][ni], 0, 0, 0);                 \
    __builtin_amdgcn_s_setprio(0);                                           \
    WAIT_STMT;                                                               \
    BARPIN();                                                                \
  }

__global__ __launch_bounds__(512, 2) void qlinear_gemm_256_kernel(
    const uint16_t* __restrict__ Xb,  // [M][K] bf16
    const uint16_t* __restrict__ Wb,  // [N][K] bf16
    const float* __restrict__ scalep,
    const float* __restrict__ bias,
    float* __restrict__ Y)
{
  constexpr int N = 16384, K = 4096;
  constexpr int RSB = K * 2;   // panel row stride, bytes
  constexpr int NT = K / 64;   // 64 K-tiles

  extern __shared__ __align__(16) char lds[];  // 131072 B

  const int tid  = threadIdx.x;
  const int lane = tid & 63;
  const int wid  = tid >> 6;   // 0..7
  const int wm   = wid >> 2;   // 0..1  (M-half of block)
  const int wn   = wid & 3;    // 0..3  (N-quarter of block)
  const int r16  = lane & 15;
  const int g4   = lane >> 4;  // logical k-chunk 0..3
  const int chb  = (g4 ^ ((r16 >> 1) & 3)) << 4;  // swizzled chunk byte off

  const int srow = tid >> 2;                              // 0..127
  const int skch = ((tid & 3) ^ ((tid >> 3) & 3)) * 16;   // pre-swizzled src

  // ---- 2D super-tile mapping: grid 2048 = 32 bm x 64 bn ----
  // XCD k (= bid&7) owns one 16x16 patch: (pr,pc) = (k&1, k>>1) over a
  // 2x4 patch grid. Local index row-major within the patch, so the ~32
  // concurrently-resident blocks per XCD are 2 patch-rows sharing X-panels
  // (4 MB, L2-resident) and 16 W-panels (32 MB, L3-resident). Union over
  // all XCDs = X + W = 192 MB < 256 MB L3, re-touched all dispatch long.
  const int bid = blockIdx.x;
  const int xcd = bid & 7;
  const int l   = bid >> 3;          // 0..255
  const int bm  = (xcd & 1) * 16 + (l >> 4);
  const int bn  = (xcd >> 1) * 16 + (l & 15);

  f32x4 acc[8][4];
#pragma unroll
  for (int i = 0; i < 8; ++i)
#pragma unroll
    for (int j = 0; j < 4; ++j) acc[i][j] = (f32x4)0.f;

  bf16x8s aq[4], bq[4];

  const char* Xp = (const char*)Xb + (size_t)(bm * 256) * RSB;
  const char* Wp = (const char*)Wb + (size_t)(bn * 256) * RSB;

  // ---- prologue: tile0 (both K-halves) + tile1 K-half0 ----
  STAGE(Xp, 0,   ABLK(lds, 0));
  STAGE(Wp, 0,   BBLK(lds, 0));
  STAGE(Xp, 64,  ABLK(lds, 1));
  STAGE(Wp, 64,  BBLK(lds, 1));
  STAGE(Xp, 128, ABLK(lds + 65536, 0));
  STAGE(Wp, 128, BBLK(lds + 65536, 0));
  WAIT8;        // drains tile0 k0 (A,B); leaves 4 units in flight
  BARPIN();

  // ---- main loop: tiles 0 .. NT-3 ----
  for (int t = 0; t <= NT - 3; ++t) {
    char* cb = lds + ((t & 1) << 16);
    char* nb = lds + (((t + 1) & 1) << 16);
    const size_t k1n = (size_t)(t + 1) * 128;
    const size_t k2n = (size_t)(t + 2) * 128;
    PHASE(ABLK(cb, 0), BBLK(cb, 0), 0, true,  STAGE(Xp, k1n + 64, ABLK(nb, 1)), );
    PHASE(ABLK(cb, 0), BBLK(cb, 0), 1, false, STAGE(Wp, k1n + 64, BBLK(nb, 1)), WAIT8);
    PHASE(ABLK(cb, 1), BBLK(cb, 1), 0, true,  STAGE(Xp, k2n,      ABLK(cb, 0)), );
    PHASE(ABLK(cb, 1), BBLK(cb, 1), 1, false, STAGE(Wp, k2n,      BBLK(cb, 0)), WAIT8);
  }

  // ---- tail ----
  {
    const int t = NT - 2;
    char* cb = lds + ((t & 1) << 16);
    char* nb = lds + (((t + 1) & 1) << 16);
    const size_t k1n = (size_t)(t + 1) * 128;
    PHASE(ABLK(cb, 0), BBLK(cb, 0), 0, true,  STAGE(Xp, k1n + 64, ABLK(nb, 1)), );
    PHASE(ABLK(cb, 0), BBLK(cb, 0), 1, false, STAGE(Wp, k1n + 64, BBLK(nb, 1)), WAIT8);
    PHASE(ABLK(cb, 1), BBLK(cb, 1), 0, true,  , );
    PHASE(ABLK(cb, 1), BBLK(cb, 1), 1, false, , WAIT4);
  }
  {
    const int t = NT - 1;
    char* cb = lds + ((t & 1) << 16);
    PHASE(ABLK(cb, 0), BBLK(cb, 0), 0, true,  , );
    PHASE(ABLK(cb, 0), BBLK(cb, 0), 1, false, , WAIT0);
    PHASE(ABLK(cb, 1), BBLK(cb, 1), 0, true,  , );
    PHASE(ABLK(cb, 1), BBLK(cb, 1), 1, false, , );
  }

  // ---- epilogue: y = scale*acc + bias ----
  // C/D layout: col = lane&15, row = (lane>>4)*4 + reg  [m89/m91-verified]
  const float s = scalep[0];
  float bv[4];
#pragma unroll
  for (int ni = 0; ni < 4; ++ni)
    bv[ni] = bias[bn * 256 + wn * 64 + ni * 16 + r16];

#pragma unroll
  for (int mi = 0; mi < 8; ++mi) {
    const int grow0 = bm * 256 + wm * 128 + mi * 16 + g4 * 4;
#pragma unroll
    for (int r = 0; r < 4; ++r) {
      float* yp = Y + (size_t)(grow0 + r) * N + bn * 256 + wn * 64 + r16;
#pragma unroll
      for (int ni = 0; ni < 4; ++ni)
        yp[ni * 16] = s * acc[mi][ni][r] + bv[ni];
    }
  }
}

// ---------------- fallback: fused kernel (if ws too small) ----------------
#define BM 128
#define BN 128
#define BK 64
#define LDKF (BK * 2)

__global__ __launch_bounds__(256, 2) void qlinear_fused_kernel(
    const float* __restrict__ X, const int32_t* __restrict__ W,
    const float* __restrict__ scalep, const float* __restrict__ bias,
    float* __restrict__ Y)
{
  constexpr int N = 16384, K = 4096;
  __shared__ __align__(16) char slds[(BM + BN) * LDKF];
  char* As = slds;
  char* Bs = slds + BM * LDKF;
  const int tid = threadIdx.x, lane = tid & 63, wid = tid >> 6;
  const int wr = wid >> 1, wc = wid & 1;
  const int nwg = gridDim.x, cpx = nwg >> 3, bid = blockIdx.x;
  const int swz = (bid & 7) * cpx + (bid >> 3);
  const int ntn = N / BN, bm = swz / ntn, bn = swz % ntn;
  const int r16 = lane & 15, g4 = lane >> 4;
  f32x4 acc[4][4];
#pragma unroll
  for (int i = 0; i < 4; ++i)
#pragma unroll
    for (int j = 0; j < 4; ++j) acc[i][j] = (f32x4)0.f;
  const float* Abase = X + (size_t)(bm * BM) * K;
  const int32_t* Bbase = W + (size_t)(bn * BN) * K;
  const int stg_col = (tid & 7) * 8;
  for (int kt = 0; kt < K / BK; ++kt) {
    const int kb = kt * BK;
    if (kt) __syncthreads();
#pragma unroll
    for (int i = 0; i < 4; ++i) {
      const int row = i * 32 + (tid >> 3);
      const float* p = Abase + (size_t)row * K + kb + stg_col;
      f32x4 v0 = *(const f32x4*)p;
      f32x4 v1 = *(const f32x4*)(p + 4);
      u32x4 o = {pk2_rne(v0.x, v0.y), pk2_rne(v0.z, v0.w),
                 pk2_rne(v1.x, v1.y), pk2_rne(v1.z, v1.w)};
      int byte = (row * LDKF + stg_col * 2) ^ ((row & 7) << 4);
      *(u32x4*)(As + byte) = o;
    }
#pragma unroll
    for (int i = 0; i < 4; ++i) {
      const int row = i * 32 + (tid >> 3);
      const int32_t* p = Bbase + (size_t)row * K + kb + stg_col;
      i32x4 v0 = *(const i32x4*)p;
      i32x4 v1 = *(const i32x4*)(p + 4);
      u32x4 o = {pk2_trunc((float)v0.x, (float)v0.y),
                 pk2_trunc((float)v0.z, (float)v0.w),
                 pk2_trunc((float)v1.x, (float)v1.y),
                 pk2_trunc((float)v1.z, (float)v1.w)};
      int byte = (row * LDKF + stg_col * 2) ^ ((row & 7) << 4);
      *(u32x4*)(Bs + byte) = o;
    }
    __syncthreads();
#pragma unroll
    for (int kk = 0; kk < 2; ++kk) {
      bf16x8s af[4], bfr[4];
#pragma unroll
      for (int mi = 0; mi < 4; ++mi) {
        const int row = wr * 64 + mi * 16 + r16;
        int byte = (row * LDKF + kk * 64 + g4 * 16) ^ ((row & 7) << 4);
        af[mi] = *(const bf16x8s*)(As + byte);
      }
#pragma unroll
      for (int ni = 0; ni < 4; ++ni) {
        const int row = wc * 64 + ni * 16 + r16;
        int byte = (row * LDKF + kk * 64 + g4 * 16) ^ ((row & 7) << 4);
        bfr[ni] = *(const bf16x8s*)(Bs + byte);
      }
#pragma unroll
      for (int mi = 0; mi < 4; ++mi)
#pragma unroll
        for (int ni = 0; ni < 4; ++ni)
          acc[mi][ni] = __builtin_amdgcn_mfma_f32_16x16x32_bf16(
              af[mi], bfr[ni], acc[mi][ni], 0, 0, 0);
    }
  }
  const float s = scalep[0];
  float bv[4];
#pragma unroll
  for (int ni = 0; ni < 4; ++ni)
    bv[ni] = bias[bn * BN + wc * 64 + ni * 16 + r16];
#pragma unroll
  for (int mi = 0; mi < 4; ++mi) {
    const int grow0 = bm * BM + wr * 64 + mi * 16 + g4 * 4;
#pragma unroll
    for (int r = 0; r < 4; ++r) {
      float* yp = Y + (size_t)(grow0 + r) * N + bn * BN + wc * 64 + r16;
#pragma unroll
      for (int ni = 0; ni < 4; ++ni)
        yp[ni * 16] = s * acc[mi][ni][r] + bv[ni];
    }
  }
}

extern "C" void kernel_launch(void* const* d_in, const int* in_sizes, int n_in,
                              void* d_out, int out_size, void* d_ws, size_t ws_size,
                              hipStream_t stream) {
  const float*   x  = (const float*)d_in[0];
  const int32_t* w  = (const int32_t*)d_in[1];
  const float*   sc = (const float*)d_in[2];
  const float*   bs = (const float*)d_in[3];
  float*         y  = (float*)d_out;

  constexpr size_t M = 8192, N = 16384, K = 4096;
  const size_t xb_elems = M * K;   // 64 MB bf16
  const size_t wb_elems = N * K;   // 128 MB bf16
  const size_t need = (xb_elems + wb_elems) * 2;

  if (ws_size >= need) {
    uint16_t* xb = (uint16_t*)d_ws;
    uint16_t* wb = xb + xb_elems;
    hipFuncSetAttribute((const void*)qlinear_gemm_256_kernel,
                        hipFuncAttributeMaxDynamicSharedMemorySize, 131072);
    conv_x_kernel<<<2048, 256, 0, stream>>>(x, xb, (int)(xb_elems / 8));
    conv_w_kernel<<<2048, 256, 0, stream>>>(w, wb, (int)(wb_elems / 8));
    qlinear_gemm_256_kernel<<<2048, 512, 131072, stream>>>(xb, wb, sc, bs, y);
  } else {
    qlinear_fused_kernel<<<8192, 256, 0, stream>>>(x, w, sc, bs, y);
  }
}

// Round 7
// 1007.927 us; speedup vs baseline: 2.9422x; 1.0088x over previous
//
#include <hip/hip_runtime.h>
#include <hip/hip_bf16.h>
#include <stdint.h>

// QuantizedLinear: Y[M][N] = scale * (X[M][K] @ W[N][K]^T) + bias[N]
// M=8192, K=4096, N=16384. X fp32, W int32 (harness widens int8), out fp32.
// Round 7: schedule relaxation — 1 barrier per phase (4/tile, was 8),
// sched_barrier pins removed (kept only after vmcnt asm), STAGE issued
// first in each phase. Traffic structure (super-tile mapping, swizzle,
// counted vmcnt) frozen from round 6.

typedef __attribute__((ext_vector_type(4))) float f32x4;
typedef __attribute__((ext_vector_type(4))) int i32x4;
typedef __attribute__((ext_vector_type(8))) short bf16x8s;
typedef __attribute__((ext_vector_type(4))) unsigned int u32x4;

__device__ __forceinline__ uint32_t f2bf_rne(float f) {
  uint32_t x = __float_as_uint(f);
  return (x + 0x7FFFu + ((x >> 16) & 1u)) >> 16;
}
__device__ __forceinline__ uint32_t pk2_rne(float lo, float hi) {
  return f2bf_rne(lo) | (f2bf_rne(hi) << 16);
}
__device__ __forceinline__ uint32_t pk2_trunc(float lo, float hi) {
  return (__float_as_uint(lo) >> 16) | (__float_as_uint(hi) & 0xFFFF0000u);
}

#define GLOAD_LDS16(g, l)                                        \
  __builtin_amdgcn_global_load_lds(                              \
      (const __attribute__((address_space(1))) void*)(g),        \
      (__attribute__((address_space(3))) void*)(l), 16, 0, 0)

// ---------------- conversion kernels (NT loads: inputs are read-once) ------
__global__ __launch_bounds__(256) void conv_x_kernel(
    const float* __restrict__ x, uint16_t* __restrict__ out, int n8) {
  const int stride = blockDim.x * gridDim.x;
  for (int i = blockIdx.x * blockDim.x + threadIdx.x; i < n8; i += stride) {
    f32x4 v0 = __builtin_nontemporal_load((const f32x4*)x + i * 2);
    f32x4 v1 = __builtin_nontemporal_load((const f32x4*)x + i * 2 + 1);
    u32x4 o;
    o.x = pk2_rne(v0.x, v0.y);
    o.y = pk2_rne(v0.z, v0.w);
    o.z = pk2_rne(v1.x, v1.y);
    o.w = pk2_rne(v1.z, v1.w);
    ((u32x4*)out)[i] = o;
  }
}

__global__ __launch_bounds__(256) void conv_w_kernel(
    const int32_t* __restrict__ w, uint16_t* __restrict__ out, int n8) {
  const int stride = blockDim.x * gridDim.x;
  for (int i = blockIdx.x * blockDim.x + threadIdx.x; i < n8; i += stride) {
    i32x4 v0 = __builtin_nontemporal_load((const i32x4*)w + i * 2);
    i32x4 v1 = __builtin_nontemporal_load((const i32x4*)w + i * 2 + 1);
    u32x4 o;
    o.x = pk2_trunc((float)v0.x, (float)v0.y);
    o.y = pk2_trunc((float)v0.z, (float)v0.w);
    o.z = pk2_trunc((float)v1.x, (float)v1.y);
    o.w = pk2_trunc((float)v1.z, (float)v1.w);
    ((u32x4*)out)[i] = o;
  }
}

// ---------------- 256x256 GEMM, 4 phases/K-tile, 1 barrier/phase ----------
// LDS layout (dynamic, 131072 B): buf b at b*65536; A at +0, B at +32768;
// within A/B: K-half block kk at kk*16384 = [256 rows][32 bf16] (64 B rows).
// Swizzle: physical 16B-chunk = logical_chunk ^ ((row>>1)&3)  (involution).
// Staged via pre-swizzled GLOBAL source + linear LDS dest (rule #21).
//
// Hazard anchors: (a) each phase's ds_reads are consumed by its own MFMAs
// (lgkmcnt) before the wave reaches the phase-end barrier; (b) every STAGE
// targets a region last read >=1 phase earlier (barrier between); (c) the
// counted-vmcnt asm (memory clobber) orders gload_lds vs later ds_reads.

#define BARRIER() __builtin_amdgcn_s_barrier()

#define WAIT8 asm volatile("s_waitcnt vmcnt(8)" ::: "memory"); __builtin_amdgcn_sched_barrier(0)
#define WAIT4 asm volatile("s_waitcnt vmcnt(4)" ::: "memory"); __builtin_amdgcn_sched_barrier(0)
#define WAIT0 asm volatile("s_waitcnt vmcnt(0)" ::: "memory"); __builtin_amdgcn_sched_barrier(0)

#define STAGE(mat_base, koffb, ldsbase)                                      \
  {                                                                          \
    GLOAD_LDS16((mat_base) + (size_t)srow * RSB + (koffb) + skch,            \
                (ldsbase) + tid * 16);                                       \
    GLOAD_LDS16((mat_base) + (size_t)(srow + 128) * RSB + (koffb) + skch,    \
                (ldsbase) + 8192 + tid * 16);                                \
  }

#define ABLK(buf, kk) ((buf) + (kk) * 16384)
#define BBLK(buf, kk) ((buf) + 32768 + (kk) * 16384)

#define PHASE(Abase, Bbase, mih, READB, STAGE_STMT, WAIT_STMT)               \
  {                                                                          \
    STAGE_STMT;                                                              \
    if (READB) {                                                             \
      _Pragma("unroll") for (int ni = 0; ni < 4; ++ni) {                     \
        const int r_ = wn * 64 + ni * 16 + r16;                              \
        bq[ni] = *(const bf16x8s*)((Bbase) + r_ * 64 + chb);                 \
      }                                                                      \
    }                                                                        \
    _Pragma("unroll") for (int i = 0; i < 4; ++i) {                          \
      const int r_ = wm * 128 + ((mih) * 4 + i) * 16 + r16;                  \
      aq[i] = *(const bf16x8s*)((Abase) + r_ * 64 + chb);                    \
    }                                                                        \
    __builtin_amdgcn_s_setprio(1);                                           \
    _Pragma("unroll") for (int i = 0; i < 4; ++i)                            \
      _Pragma("unroll") for (int ni = 0; ni < 4; ++ni)                       \
        acc[(mih) * 4 + i][ni] = __builtin_amdgcn_mfma_f32_16x16x32_bf16(    \
            aq[i], bq[ni], acc[(mih) * 4 + i][ni], 0, 0, 0);                 \
    __builtin_amdgcn_s_setprio(0);                                           \
    WAIT_STMT;                                                               \
    BARRIER();                                                               \
  }

__global__ __launch_bounds__(512, 2) void qlinear_gemm_256_kernel(
    const uint16_t* __restrict__ Xb,  // [M][K] bf16
    const uint16_t* __restrict__ Wb,  // [N][K] bf16
    const float* __restrict__ scalep,
    const float* __restrict__ bias,
    float* __restrict__ Y)
{
  constexpr int N = 16384, K = 4096;
  constexpr int RSB = K * 2;   // panel row stride, bytes
  constexpr int NT = K / 64;   // 64 K-tiles

  extern __shared__ __align__(16) char lds[];  // 131072 B

  const int tid  = threadIdx.x;
  const int lane = tid & 63;
  const int wid  = tid >> 6;   // 0..7
  const int wm   = wid >> 2;   // 0..1  (M-half of block)
  const int wn   = wid & 3;    // 0..3  (N-quarter of block)
  const int r16  = lane & 15;
  const int g4   = lane >> 4;  // logical k-chunk 0..3
  const int chb  = (g4 ^ ((r16 >> 1) & 3)) << 4;  // swizzled chunk byte off

  const int srow = tid >> 2;                              // 0..127
  const int skch = ((tid & 3) ^ ((tid >> 3) & 3)) * 16;   // pre-swizzled src

  // ---- 2D super-tile mapping: grid 2048 = 32 bm x 64 bn ----
  // XCD k (= bid&7) owns one 16x16 patch: (pr,pc) = (k&1, k>>1) over a
  // 2x4 patch grid. Working set X 64MB + W 128MB = 192MB stays L3-resident.
  const int bid = blockIdx.x;
  const int xcd = bid & 7;
  const int l   = bid >> 3;          // 0..255
  const int bm  = (xcd & 1) * 16 + (l >> 4);
  const int bn  = (xcd >> 1) * 16 + (l & 15);

  f32x4 acc[8][4];
#pragma unroll
  for (int i = 0; i < 8; ++i)
#pragma unroll
    for (int j = 0; j < 4; ++j) acc[i][j] = (f32x4)0.f;

  bf16x8s aq[4], bq[4];

  const char* Xp = (const char*)Xb + (size_t)(bm * 256) * RSB;
  const char* Wp = (const char*)Wb + (size_t)(bn * 256) * RSB;

  // ---- prologue: tile0 (both K-halves) + tile1 K-half0 ----
  STAGE(Xp, 0,   ABLK(lds, 0));
  STAGE(Wp, 0,   BBLK(lds, 0));
  STAGE(Xp, 64,  ABLK(lds, 1));
  STAGE(Wp, 64,  BBLK(lds, 1));
  STAGE(Xp, 128, ABLK(lds + 65536, 0));
  STAGE(Wp, 128, BBLK(lds + 65536, 0));
  WAIT8;        // drains tile0 k0 (A,B); leaves 4 units in flight
  BARRIER();

  // ---- main loop: tiles 0 .. NT-3 ----
  for (int t = 0; t <= NT - 3; ++t) {
    char* cb = lds + ((t & 1) << 16);
    char* nb = lds + (((t + 1) & 1) << 16);
    const size_t k1n = (size_t)(t + 1) * 128;
    const size_t k2n = (size_t)(t + 2) * 128;
    PHASE(ABLK(cb, 0), BBLK(cb, 0), 0, true,  STAGE(Xp, k1n + 64, ABLK(nb, 1)), );
    PHASE(ABLK(cb, 0), BBLK(cb, 0), 1, false, STAGE(Wp, k1n + 64, BBLK(nb, 1)), WAIT8);
    PHASE(ABLK(cb, 1), BBLK(cb, 1), 0, true,  STAGE(Xp, k2n,      ABLK(cb, 0)), );
    PHASE(ABLK(cb, 1), BBLK(cb, 1), 1, false, STAGE(Wp, k2n,      BBLK(cb, 0)), WAIT8);
  }

  // ---- tail ----
  {
    const int t = NT - 2;
    char* cb = lds + ((t & 1) << 16);
    char* nb = lds + (((t + 1) & 1) << 16);
    const size_t k1n = (size_t)(t + 1) * 128;
    PHASE(ABLK(cb, 0), BBLK(cb, 0), 0, true,  STAGE(Xp, k1n + 64, ABLK(nb, 1)), );
    PHASE(ABLK(cb, 0), BBLK(cb, 0), 1, false, STAGE(Wp, k1n + 64, BBLK(nb, 1)), WAIT8);
    PHASE(ABLK(cb, 1), BBLK(cb, 1), 0, true,  , );
    PHASE(ABLK(cb, 1), BBLK(cb, 1), 1, false, , WAIT4);
  }
  {
    const int t = NT - 1;
    char* cb = lds + ((t & 1) << 16);
    PHASE(ABLK(cb, 0), BBLK(cb, 0), 0, true,  , );
    PHASE(ABLK(cb, 0), BBLK(cb, 0), 1, false, , WAIT0);
    PHASE(ABLK(cb, 1), BBLK(cb, 1), 0, true,  , );
    PHASE(ABLK(cb, 1), BBLK(cb, 1), 1, false, , );
  }

  // ---- epilogue: y = scale*acc + bias ----
  // C/D layout: col = lane&15, row = (lane>>4)*4 + reg  [m89/m91-verified]
  const float s = scalep[0];
  float bv[4];
#pragma unroll
  for (int ni = 0; ni < 4; ++ni)
    bv[ni] = bias[bn * 256 + wn * 64 + ni * 16 + r16];

#pragma unroll
  for (int mi = 0; mi < 8; ++mi) {
    const int grow0 = bm * 256 + wm * 128 + mi * 16 + g4 * 4;
#pragma unroll
    for (int r = 0; r < 4; ++r) {
      float* yp = Y + (size_t)(grow0 + r) * N + bn * 256 + wn * 64 + r16;
#pragma unroll
      for (int ni = 0; ni < 4; ++ni)
        yp[ni * 16] = s * acc[mi][ni][r] + bv[ni];
    }
  }
}

// ---------------- fallback: fused kernel (if ws too small) ----------------
#define BM 128
#define BN 128
#define BK 64
#define LDKF (BK * 2)

__global__ __launch_bounds__(256, 2) void qlinear_fused_kernel(
    const float* __restrict__ X, const int32_t* __restrict__ W,
    const float* __restrict__ scalep, const float* __restrict__ bias,
    float* __restrict__ Y)
{
  constexpr int N = 16384, K = 4096;
  __shared__ __align__(16) char slds[(BM + BN) * LDKF];
  char* As = slds;
  char* Bs = slds + BM * LDKF;
  const int tid = threadIdx.x, lane = tid & 63, wid = tid >> 6;
  const int wr = wid >> 1, wc = wid & 1;
  const int nwg = gridDim.x, cpx = nwg >> 3, bid = blockIdx.x;
  const int swz = (bid & 7) * cpx + (bid >> 3);
  const int ntn = N / BN, bm = swz / ntn, bn = swz % ntn;
  const int r16 = lane & 15, g4 = lane >> 4;
  f32x4 acc[4][4];
#pragma unroll
  for (int i = 0; i < 4; ++i)
#pragma unroll
    for (int j = 0; j < 4; ++j) acc[i][j] = (f32x4)0.f;
  const float* Abase = X + (size_t)(bm * BM) * K;
  const int32_t* Bbase = W + (size_t)(bn * BN) * K;
  const int stg_col = (tid & 7) * 8;
  for (int kt = 0; kt < K / BK; ++kt) {
    const int kb = kt * BK;
    if (kt) __syncthreads();
#pragma unroll
    for (int i = 0; i < 4; ++i) {
      const int row = i * 32 + (tid >> 3);
      const float* p = Abase + (size_t)row * K + kb + stg_col;
      f32x4 v0 = *(const f32x4*)p;
      f32x4 v1 = *(const f32x4*)(p + 4);
      u32x4 o = {pk2_rne(v0.x, v0.y), pk2_rne(v0.z, v0.w),
                 pk2_rne(v1.x, v1.y), pk2_rne(v1.z, v1.w)};
      int byte = (row * LDKF + stg_col * 2) ^ ((row & 7) << 4);
      *(u32x4*)(As + byte) = o;
    }
#pragma unroll
    for (int i = 0; i < 4; ++i) {
      const int row = i * 32 + (tid >> 3);
      const int32_t* p = Bbase + (size_t)row * K + kb + stg_col;
      i32x4 v0 = *(const i32x4*)p;
      i32x4 v1 = *(const i32x4*)(p + 4);
      u32x4 o = {pk2_trunc((float)v0.x, (float)v0.y),
                 pk2_trunc((float)v0.z, (float)v0.w),
                 pk2_trunc((float)v1.x, (float)v1.y),
                 pk2_trunc((float)v1.z, (float)v1.w)};
      int byte = (row * LDKF + stg_col * 2) ^ ((row & 7) << 4);
      *(u32x4*)(Bs + byte) = o;
    }
    __syncthreads();
#pragma unroll
    for (int kk = 0; kk < 2; ++kk) {
      bf16x8s af[4], bfr[4];
#pragma unroll
      for (int mi = 0; mi < 4; ++mi) {
        const int row = wr * 64 + mi * 16 + r16;
        int byte = (row * LDKF + kk * 64 + g4 * 16) ^ ((row & 7) << 4);
        af[mi] = *(const bf16x8s*)(As + byte);
      }
#pragma unroll
      for (int ni = 0; ni < 4; ++ni) {
        const int row = wc * 64 + ni * 16 + r16;
        int byte = (row * LDKF + kk * 64 + g4 * 16) ^ ((row & 7) << 4);
        bfr[ni] = *(const bf16x8s*)(Bs + byte);
      }
#pragma unroll
      for (int mi = 0; mi < 4; ++mi)
#pragma unroll
        for (int ni = 0; ni < 4; ++ni)
          acc[mi][ni] = __builtin_amdgcn_mfma_f32_16x16x32_bf16(
              af[mi], bfr[ni], acc[mi][ni], 0, 0, 0);
    }
  }
  const float s = scalep[0];
  float bv[4];
#pragma unroll
  for (int ni = 0; ni < 4; ++ni)
    bv[ni] = bias[bn * BN + wc * 64 + ni * 16 + r16];
#pragma unroll
  for (int mi = 0; mi < 4; ++mi) {
    const int grow0 = bm * BM + wr * 64 + mi * 16 + g4 * 4;
#pragma unroll
    for (int r = 0; r < 4; ++r) {
      float* yp = Y + (size_t)(grow0 + r) * N + bn * BN + wc * 64 + r16;
#pragma unroll
      for (int ni = 0; ni < 4; ++ni)
        yp[ni * 16] = s * acc[mi][ni][r] + bv[ni];
    }
  }
}

extern "C" void kernel_launch(void* const* d_in, const int* in_sizes, int n_in,
                              void* d_out, int out_size, void* d_ws, size_t ws_size,
                              hipStream_t stream) {
  const float*   x  = (const float*)d_in[0];
  const int32_t* w  = (const int32_t*)d_in[1];
  const float*   sc = (const float*)d_in[2];
  const float*   bs = (const float*)d_in[3];
  float*         y  = (float*)d_out;

  constexpr size_t M = 8192, N = 16384, K = 4096;
  const size_t xb_elems = M * K;   // 64 MB bf16
  const size_t wb_elems = N * K;   // 128 MB bf16
  const size_t need = (xb_elems + wb_elems) * 2;

  if (ws_size >= need) {
    uint16_t* xb = (uint16_t*)d_ws;
    uint16_t* wb = xb + xb_elems;
    hipFuncSetAttribute((const void*)qlinear_gemm_256_kernel,
                        hipFuncAttributeMaxDynamicSharedMemorySize, 131072);
    conv_x_kernel<<<2048, 256, 0, stream>>>(x, xb, (int)(xb_elems / 8));
    conv_w_kernel<<<2048, 256, 0, stream>>>(w, wb, (int)(wb_elems / 8));
    qlinear_gemm_256_kernel<<<2048, 512, 131072, stream>>>(xb, wb, sc, bs, y);
  } else {
    qlinear_fused_kernel<<<8192, 256, 0, stream>>>(x, w, sc, bs, y);
  }
}

// Round 8
// 993.249 us; speedup vs baseline: 2.9857x; 1.0148x over previous
//
#include <hip/hip_runtime.h>
#include <hip/hip_bf16.h>
#include <stdint.h>

// QuantizedLinear: Y[M][N] = scale * (X[M][K] @ W[N][K]^T) + bias[N]
// M=8192, K=4096, N=16384. X fp32, W int32 (harness widens int8), out fp32.
// Round 8: 2-epoch K-tile. Each epoch = {2 STAGEs, 12 ds_reads up front,
// 2x16 MFMA clusters} + WAIT8 + barrier. Reads for cluster 1 overlap
// cluster 0's MFMAs (counted lgkmcnt by compiler); no mid-epoch barrier ->
// waves stagger, LDS pipe overlaps matrix pipe. Traffic structure
// (super-tile map, swizzle, vmcnt accounting) frozen from rounds 6-7.

typedef __attribute__((ext_vector_type(4))) float f32x4;
typedef __attribute__((ext_vector_type(4))) int i32x4;
typedef __attribute__((ext_vector_type(8))) short bf16x8s;
typedef __attribute__((ext_vector_type(4))) unsigned int u32x4;

__device__ __forceinline__ uint32_t f2bf_rne(float f) {
  uint32_t x = __float_as_uint(f);
  return (x + 0x7FFFu + ((x >> 16) & 1u)) >> 16;
}
__device__ __forceinline__ uint32_t pk2_rne(float lo, float hi) {
  return f2bf_rne(lo) | (f2bf_rne(hi) << 16);
}
__device__ __forceinline__ uint32_t pk2_trunc(float lo, float hi) {
  return (__float_as_uint(lo) >> 16) | (__float_as_uint(hi) & 0xFFFF0000u);
}

#define GLOAD_LDS16(g, l)                                        \
  __builtin_amdgcn_global_load_lds(                              \
      (const __attribute__((address_space(1))) void*)(g),        \
      (__attribute__((address_space(3))) void*)(l), 16, 0, 0)

// ---------------- conversion kernels (NT loads: inputs are read-once) ------
__global__ __launch_bounds__(256) void conv_x_kernel(
    const float* __restrict__ x, uint16_t* __restrict__ out, int n8) {
  const int stride = blockDim.x * gridDim.x;
  for (int i = blockIdx.x * blockDim.x + threadIdx.x; i < n8; i += stride) {
    f32x4 v0 = __builtin_nontemporal_load((const f32x4*)x + i * 2);
    f32x4 v1 = __builtin_nontemporal_load((const f32x4*)x + i * 2 + 1);
    u32x4 o;
    o.x = pk2_rne(v0.x, v0.y);
    o.y = pk2_rne(v0.z, v0.w);
    o.z = pk2_rne(v1.x, v1.y);
    o.w = pk2_rne(v1.z, v1.w);
    ((u32x4*)out)[i] = o;
  }
}

__global__ __launch_bounds__(256) void conv_w_kernel(
    const int32_t* __restrict__ w, uint16_t* __restrict__ out, int n8) {
  const int stride = blockDim.x * gridDim.x;
  for (int i = blockIdx.x * blockDim.x + threadIdx.x; i < n8; i += stride) {
    i32x4 v0 = __builtin_nontemporal_load((const i32x4*)w + i * 2);
    i32x4 v1 = __builtin_nontemporal_load((const i32x4*)w + i * 2 + 1);
    u32x4 o;
    o.x = pk2_trunc((float)v0.x, (float)v0.y);
    o.y = pk2_trunc((float)v0.z, (float)v0.w);
    o.z = pk2_trunc((float)v1.x, (float)v1.y);
    o.w = pk2_trunc((float)v1.z, (float)v1.w);
    ((u32x4*)out)[i] = o;
  }
}

// ---------------- 256x256 GEMM, 2 epochs/K-tile ----------------
// LDS layout (dynamic, 131072 B): buf b at b*65536; A at +0, B at +32768;
// within A/B: K-half block kk at kk*16384 = [256 rows][32 bf16] (64 B rows).
// Swizzle: physical 16B-chunk = logical_chunk ^ ((row>>1)&3)  (involution).
// Staged via pre-swizzled GLOBAL source + linear LDS dest (rule #21).
//
// Hazard anchors: (a) kk1 reads sit AFTER epoch-A's WAIT8+barrier (staging
// of (t,k1) confirmed exactly there); (b) epoch-B's STAGE into cb.k0 is
// barrier-separated from epoch-A's kk0 reads (every wave's MFMAs consume
// its reads via lgkmcnt before it reaches the barrier); (c) WAIT8 drains
// 12->8 outstanding, retiring the 2-epoch-old stage pair (induction
// verified incl. prologue and tails).

#define BARRIER() __builtin_amdgcn_s_barrier()

#define WAIT8 asm volatile("s_waitcnt vmcnt(8)" ::: "memory"); __builtin_amdgcn_sched_barrier(0)
#define WAIT4 asm volatile("s_waitcnt vmcnt(4)" ::: "memory"); __builtin_amdgcn_sched_barrier(0)
#define WAIT0 asm volatile("s_waitcnt vmcnt(0)" ::: "memory"); __builtin_amdgcn_sched_barrier(0)

#define STAGE(mat_base, koffb, ldsbase)                                      \
  {                                                                          \
    GLOAD_LDS16((mat_base) + (size_t)srow * RSB + (koffb) + skch,            \
                (ldsbase) + tid * 16);                                       \
    GLOAD_LDS16((mat_base) + (size_t)(srow + 128) * RSB + (koffb) + skch,    \
                (ldsbase) + 8192 + tid * 16);                                \
  }

#define ABLK(buf, kk) ((buf) + (kk) * 16384)
#define BBLK(buf, kk) ((buf) + 32768 + (kk) * 16384)

#define READA(dst, base, mih)                                                \
  _Pragma("unroll") for (int i = 0; i < 4; ++i) {                            \
    const int r_ = wm * 128 + ((mih) * 4 + i) * 16 + r16;                    \
    dst[i] = *(const bf16x8s*)((base) + r_ * 64 + chb);                      \
  }

#define READB_(dst, base)                                                    \
  _Pragma("unroll") for (int ni = 0; ni < 4; ++ni) {                         \
    const int r_ = wn * 64 + ni * 16 + r16;                                  \
    dst[ni] = *(const bf16x8s*)((base) + r_ * 64 + chb);                     \
  }

#define MFMA16(mih, aqv, bqv)                                                \
  __builtin_amdgcn_s_setprio(1);                                             \
  _Pragma("unroll") for (int i = 0; i < 4; ++i)                              \
    _Pragma("unroll") for (int ni = 0; ni < 4; ++ni)                         \
      acc[(mih) * 4 + i][ni] = __builtin_amdgcn_mfma_f32_16x16x32_bf16(      \
          aqv[i], bqv[ni], acc[(mih) * 4 + i][ni], 0, 0, 0);                 \
  __builtin_amdgcn_s_setprio(0);

__global__ __launch_bounds__(512, 2) void qlinear_gemm_256_kernel(
    const uint16_t* __restrict__ Xb,  // [M][K] bf16
    const uint16_t* __restrict__ Wb,  // [N][K] bf16
    const float* __restrict__ scalep,
    const float* __restrict__ bias,
    float* __restrict__ Y)
{
  constexpr int N = 16384, K = 4096;
  constexpr int RSB = K * 2;   // panel row stride, bytes
  constexpr int NT = K / 64;   // 64 K-tiles

  extern __shared__ __align__(16) char lds[];  // 131072 B

  const int tid  = threadIdx.x;
  const int lane = tid & 63;
  const int wid  = tid >> 6;   // 0..7
  const int wm   = wid >> 2;   // 0..1  (M-half of block)
  const int wn   = wid & 3;    // 0..3  (N-quarter of block)
  const int r16  = lane & 15;
  const int g4   = lane >> 4;  // logical k-chunk 0..3
  const int chb  = (g4 ^ ((r16 >> 1) & 3)) << 4;  // swizzled chunk byte off

  const int srow = tid >> 2;                              // 0..127
  const int skch = ((tid & 3) ^ ((tid >> 3) & 3)) * 16;   // pre-swizzled src

  // ---- 2D super-tile mapping: grid 2048 = 32 bm x 64 bn ----
  // XCD k (= bid&7) owns one 16x16 patch: (pr,pc) = (k&1, k>>1) over a
  // 2x4 patch grid. Working set X 64MB + W 128MB = 192MB stays L3-resident.
  const int bid = blockIdx.x;
  const int xcd = bid & 7;
  const int l   = bid >> 3;          // 0..255
  const int bm  = (xcd & 1) * 16 + (l >> 4);
  const int bn  = (xcd >> 1) * 16 + (l & 15);

  f32x4 acc[8][4];
#pragma unroll
  for (int i = 0; i < 8; ++i)
#pragma unroll
    for (int j = 0; j < 4; ++j) acc[i][j] = (f32x4)0.f;

  bf16x8s aqA[4], aqB[4], bqA[4], bqB[4];

  const char* Xp = (const char*)Xb + (size_t)(bm * 256) * RSB;
  const char* Wp = (const char*)Wb + (size_t)(bn * 256) * RSB;

  // ---- prologue: tile0 (both K-halves) + tile1 K-half0 ----
  STAGE(Xp, 0,   ABLK(lds, 0));
  STAGE(Wp, 0,   BBLK(lds, 0));
  STAGE(Xp, 64,  ABLK(lds, 1));
  STAGE(Wp, 64,  BBLK(lds, 1));
  STAGE(Xp, 128, ABLK(lds + 65536, 0));
  STAGE(Wp, 128, BBLK(lds + 65536, 0));
  WAIT8;        // drains tile0 k0 (A,B); leaves 4 units in flight
  BARRIER();

  // ---- main loop: tiles 0 .. NT-3 ----
  for (int t = 0; t <= NT - 3; ++t) {
    char* cb = lds + ((t & 1) << 16);
    char* nb = lds + (((t + 1) & 1) << 16);
    const size_t k1n = (size_t)(t + 1) * 128;
    const size_t k2n = (size_t)(t + 2) * 128;
    // epoch A (kk0)
    STAGE(Xp, k1n + 64, ABLK(nb, 1));
    READA(aqA, ABLK(cb, 0), 0);
    READB_(bqA, BBLK(cb, 0));
    READA(aqB, ABLK(cb, 0), 1);
    STAGE(Wp, k1n + 64, BBLK(nb, 1));
    MFMA16(0, aqA, bqA);
    MFMA16(1, aqB, bqA);
    WAIT8;
    BARRIER();
    // epoch B (kk1)
    STAGE(Xp, k2n, ABLK(cb, 0));
    READA(aqA, ABLK(cb, 1), 0);
    READB_(bqB, BBLK(cb, 1));
    READA(aqB, ABLK(cb, 1), 1);
    STAGE(Wp, k2n, BBLK(cb, 0));
    MFMA16(0, aqA, bqB);
    MFMA16(1, aqB, bqB);
    WAIT8;
    BARRIER();
  }

  // ---- tail: tile NT-2 (stages only (NT-1,k1)) ----
  {
    const int t = NT - 2;
    char* cb = lds + ((t & 1) << 16);
    char* nb = lds + (((t + 1) & 1) << 16);
    const size_t k1n = (size_t)(t + 1) * 128;
    STAGE(Xp, k1n + 64, ABLK(nb, 1));
    READA(aqA, ABLK(cb, 0), 0);
    READB_(bqA, BBLK(cb, 0));
    READA(aqB, ABLK(cb, 0), 1);
    STAGE(Wp, k1n + 64, BBLK(nb, 1));
    MFMA16(0, aqA, bqA);
    MFMA16(1, aqB, bqA);
    WAIT8;
    BARRIER();
    READA(aqA, ABLK(cb, 1), 0);
    READB_(bqB, BBLK(cb, 1));
    READA(aqB, ABLK(cb, 1), 1);
    MFMA16(0, aqA, bqB);
    MFMA16(1, aqB, bqB);
    WAIT4;    // retires (NT-1,k0) stages
    BARRIER();
  }
  // ---- tile NT-1 (no staging) ----
  {
    const int t = NT - 1;
    char* cb = lds + ((t & 1) << 16);
    READA(aqA, ABLK(cb, 0), 0);
    READB_(bqA, BBLK(cb, 0));
    READA(aqB, ABLK(cb, 0), 1);
    MFMA16(0, aqA, bqA);
    MFMA16(1, aqB, bqA);
    WAIT0;    // retires (NT-1,k1) stages
    BARRIER();
    READA(aqA, ABLK(cb, 1), 0);
    READB_(bqB, BBLK(cb, 1));
    READA(aqB, ABLK(cb, 1), 1);
    MFMA16(0, aqA, bqB);
    MFMA16(1, aqB, bqB);
  }

  // ---- epilogue: y = scale*acc + bias ----
  // C/D layout: col = lane&15, row = (lane>>4)*4 + reg  [m89/m91-verified]
  const float s = scalep[0];
  float bv[4];
#pragma unroll
  for (int ni = 0; ni < 4; ++ni)
    bv[ni] = bias[bn * 256 + wn * 64 + ni * 16 + r16];

#pragma unroll
  for (int mi = 0; mi < 8; ++mi) {
    const int grow0 = bm * 256 + wm * 128 + mi * 16 + g4 * 4;
#pragma unroll
    for (int r = 0; r < 4; ++r) {
      float* yp = Y + (size_t)(grow0 + r) * N + bn * 256 + wn * 64 + r16;
#pragma unroll
      for (int ni = 0; ni < 4; ++ni)
        yp[ni * 16] = s * acc[mi][ni][r] + bv[ni];
    }
  }
}

// ---------------- fallback: fused kernel (if ws too small) ----------------
#define BM 128
#define BN 128
#define BK 64
#define LDKF (BK * 2)

__global__ __launch_bounds__(256, 2) void qlinear_fused_kernel(
    const float* __restrict__ X, const int32_t* __restrict__ W,
    const float* __restrict__ scalep, const float* __restrict__ bias,
    float* __restrict__ Y)
{
  constexpr int N = 16384, K = 4096;
  __shared__ __align__(16) char slds[(BM + BN) * LDKF];
  char* As = slds;
  char* Bs = slds + BM * LDKF;
  const int tid = threadIdx.x, lane = tid & 63, wid = tid >> 6;
  const int wr = wid >> 1, wc = wid & 1;
  const int nwg = gridDim.x, cpx = nwg >> 3, bid = blockIdx.x;
  const int swz = (bid & 7) * cpx + (bid >> 3);
  const int ntn = N / BN, bm = swz / ntn, bn = swz % ntn;
  const int r16 = lane & 15, g4 = lane >> 4;
  f32x4 acc[4][4];
#pragma unroll
  for (int i = 0; i < 4; ++i)
#pragma unroll
    for (int j = 0; j < 4; ++j) acc[i][j] = (f32x4)0.f;
  const float* Abase = X + (size_t)(bm * BM) * K;
  const int32_t* Bbase = W + (size_t)(bn * BN) * K;
  const int stg_col = (tid & 7) * 8;
  for (int kt = 0; kt < K / BK; ++kt) {
    const int kb = kt * BK;
    if (kt) __syncthreads();
#pragma unroll
    for (int i = 0; i < 4; ++i) {
      const int row = i * 32 + (tid >> 3);
      const float* p = Abase + (size_t)row * K + kb + stg_col;
      f32x4 v0 = *(const f32x4*)p;
      f32x4 v1 = *(const f32x4*)(p + 4);
      u32x4 o = {pk2_rne(v0.x, v0.y), pk2_rne(v0.z, v0.w),
                 pk2_rne(v1.x, v1.y), pk2_rne(v1.z, v1.w)};
      int byte = (row * LDKF + stg_col * 2) ^ ((row & 7) << 4);
      *(u32x4*)(As + byte) = o;
    }
#pragma unroll
    for (int i = 0; i < 4; ++i) {
      const int row = i * 32 + (tid >> 3);
      const int32_t* p = Bbase + (size_t)row * K + kb + stg_col;
      i32x4 v0 = *(const i32x4*)p;
      i32x4 v1 = *(const i32x4*)(p + 4);
      u32x4 o = {pk2_trunc((float)v0.x, (float)v0.y),
                 pk2_trunc((float)v0.z, (float)v0.w),
                 pk2_trunc((float)v1.x, (float)v1.y),
                 pk2_trunc((float)v1.z, (float)v1.w)};
      int byte = (row * LDKF + stg_col * 2) ^ ((row & 7) << 4);
      *(u32x4*)(Bs + byte) = o;
    }
    __syncthreads();
#pragma unroll
    for (int kk = 0; kk < 2; ++kk) {
      bf16x8s af[4], bfr[4];
#pragma unroll
      for (int mi = 0; mi < 4; ++mi) {
        const int row = wr * 64 + mi * 16 + r16;
        int byte = (row * LDKF + kk * 64 + g4 * 16) ^ ((row & 7) << 4);
        af[mi] = *(const bf16x8s*)(As + byte);
      }
#pragma unroll
      for (int ni = 0; ni < 4; ++ni) {
        const int row = wc * 64 + ni * 16 + r16;
        int byte = (row * LDKF + kk * 64 + g4 * 16) ^ ((row & 7) << 4);
        bfr[ni] = *(const bf16x8s*)(Bs + byte);
      }
#pragma unroll
      for (int mi = 0; mi < 4; ++mi)
#pragma unroll
        for (int ni = 0; ni < 4; ++ni)
          acc[mi][ni] = __builtin_amdgcn_mfma_f32_16x16x32_bf16(
              af[mi], bfr[ni], acc[mi][ni], 0, 0, 0);
    }
  }
  const float s = scalep[0];
  float bv[4];
#pragma unroll
  for (int ni = 0; ni < 4; ++ni)
    bv[ni] = bias[bn * BN + wc * 64 + ni * 16 + r16];
#pragma unroll
  for (int mi = 0; mi < 4; ++mi) {
    const int grow0 = bm * BM + wr * 64 + mi * 16 + g4 * 4;
#pragma unroll
    for (int r = 0; r < 4; ++r) {
      float* yp = Y + (size_t)(grow0 + r) * N + bn * BN + wc * 64 + r16;
#pragma unroll
      for (int ni = 0; ni < 4; ++ni)
        yp[ni * 16] = s * acc[mi][ni][r] + bv[ni];
    }
  }
}

extern "C" void kernel_launch(void* const* d_in, const int* in_sizes, int n_in,
                              void* d_out, int out_size, void* d_ws, size_t ws_size,
                              hipStream_t stream) {
  const float*   x  = (const float*)d_in[0];
  const int32_t* w  = (const int32_t*)d_in[1];
  const float*   sc = (const float*)d_in[2];
  const float*   bs = (const float*)d_in[3];
  float*         y  = (float*)d_out;

  constexpr size_t M = 8192, N = 16384, K = 4096;
  const size_t xb_elems = M * K;   // 64 MB bf16
  const size_t wb_elems = N * K;   // 128 MB bf16
  const size_t need = (xb_elems + wb_elems) * 2;

  if (ws_size >= need) {
    uint16_t* xb = (uint16_t*)d_ws;
    uint16_t* wb = xb + xb_elems;
    hipFuncSetAttribute((const void*)qlinear_gemm_256_kernel,
                        hipFuncAttributeMaxDynamicSharedMemorySize, 131072);
    conv_x_kernel<<<2048, 256, 0, stream>>>(x, xb, (int)(xb_elems / 8));
    conv_w_kernel<<<2048, 256, 0, stream>>>(w, wb, (int)(wb_elems / 8));
    qlinear_gemm_256_kernel<<<2048, 512, 131072, stream>>>(xb, wb, sc, bs, y);
  } else {
    qlinear_fused_kernel<<<8192, 256, 0, stream>>>(x, w, sc, bs, y);
  }
}